// Round 10
// baseline (1061.254 us; speedup 1.0000x reference)
//
#include <hip/hip_runtime.h>
#include <cstddef>

// Decomposable Attention Entailment forward. B=512, P=Q=128, D=H=512.
// Round 10: round-9's 128x256 tile (read ratio 0.375) but with TWO LDS
// buffers / depth-1 prefetch = 48KB (round-9's 3-buf 72KB collapsed
// occupancy to 1 block/CU -> 18% MfmaUtil, 1054us). 48KB restores the
// 2-3 blocks/CU residency that round-8 (815us) had, while keeping the
// better FLOPs-per-ds_read of the wide tile. vmcnt(6/0) counted waits.

typedef unsigned short bf16_t;
typedef __attribute__((ext_vector_type(8))) short bf16x8;   // 8 bf16 = 4 VGPRs
typedef __attribute__((ext_vector_type(4))) float f32x4;

#define HOFFE ((size_t)33554432)   // elements per sentence tensor (512*128*512)

__device__ inline float bf2f(bf16_t u) {
    return __uint_as_float((unsigned)u << 16);
}
__device__ inline bf16_t f2bf(float f) {
    unsigned v = __float_as_uint(f);
    v += 0x7FFFu + ((v >> 16) & 1u);       // round-to-nearest-even
    return (bf16_t)(v >> 16);
}
__device__ inline unsigned pk2(float a, float b) {   // low = a, high = b
    return ((unsigned)f2bf(b) << 16) | (unsigned)f2bf(a);
}

__device__ inline float4 ld4(const float* p) {
    return *reinterpret_cast<const float4*>(p);
}
__device__ inline float4 ld4(const bf16_t* p) {
    ushort4 u = *reinterpret_cast<const ushort4*>(p);
    float4 f;
    f.x = bf2f(u.x); f.y = bf2f(u.y); f.z = bf2f(u.z); f.w = bf2f(u.w);
    return f;
}
__device__ inline void st4(float* p, float4 v) {
    *reinterpret_cast<float4*>(p) = v;
}
__device__ inline void st4(bf16_t* p, float4 v) {
    ushort4 u;
    u.x = f2bf(v.x); u.y = f2bf(v.y); u.z = f2bf(v.z); u.w = f2bf(v.w);
    *reinterpret_cast<ushort4*>(p) = u;
}

// Bijective XCD swizzle (learn_hip m204).
__device__ inline int xcd_swizzle(int orig, int nwg) {
    const int q = nwg >> 3, r = nwg & 7;
    const int xcd = orig & 7, idx = orig >> 3;
    return (xcd < r ? xcd * (q + 1) : r * (q + 1) + (xcd - r) * q) + idx;
}

// ===========================================================================
// MFMA GEMM machinery
// ===========================================================================

__device__ inline void gload_lds16(const bf16_t* g, bf16_t* l) {
    __builtin_amdgcn_global_load_lds(
        (const __attribute__((address_space(1))) unsigned int*)g,
        (__attribute__((address_space(3))) unsigned int*)l, 16, 0, 0);
}

// Stage a [128 x 32] bf16 tile into 8KB LDS ([row][32] linear). 2 issues/thread.
__device__ inline void stage_bf16(const bf16_t* __restrict__ src, int ld,
                                  bf16_t* dst, int tid) {
    const int l = tid & 63, w = tid >> 6;
#pragma unroll
    for (int i = 0; i < 2; ++i) {
        const int chunk = w * 2 + i;             // 0..7 (1KB chunks)
        const int row = chunk * 16 + (l >> 2);   // 0..127
        const int ce  = (l & 3) * 8;             // element col offset
        gload_lds16(src + (size_t)row * ld + ce, dst + chunk * 512);
    }
}

__device__ inline void stage_f32(const float* __restrict__ src, int ld,
                                 bf16_t* dst, int tid) {
    const int row = tid >> 1;
    const int seg = (tid & 1) * 16;
    const float* s = src + (size_t)row * ld + seg;
    float4 f0 = ld4(s), f1 = ld4(s + 4), f2_ = ld4(s + 8), f3 = ld4(s + 12);
    uint4 u0 = { pk2(f0.x, f0.y), pk2(f0.z, f0.w), pk2(f1.x, f1.y), pk2(f1.z, f1.w) };
    uint4 u1 = { pk2(f2_.x, f2_.y), pk2(f2_.z, f2_.w), pk2(f3.x, f3.y), pk2(f3.z, f3.w) };
    *reinterpret_cast<uint4*>(dst + row * 32 + seg)     = u0;
    *reinterpret_cast<uint4*>(dst + row * 32 + seg + 8) = u1;
}

__device__ inline void stage_any(const bf16_t* src, int ld, bf16_t* dst, int tid) {
    stage_bf16(src, ld, dst, tid);
}
__device__ inline void stage_any(const float* src, int ld, bf16_t* dst, int tid) {
    stage_f32(src, ld, dst, tid);
}

__device__ inline void store_c(float* p, float v)  { *p = v; }
__device__ inline void store_c(bf16_t* p, float v) { *p = f2bf(v); }

// ---------------------------------------------------------------------------
// Pipelined MFMA GEMM, 128(M) x 256(N) block tile, wave tile 64x128.
// All-bf16 operands: C = relu?([A1 | A2] @ Wt^T). TWO LDS buffer sets (48KB);
// staging runs 1 K-tile ahead (6 gload_lds/thread per tile, issued right
// after the previous closing barrier); counted vmcnt(6/0).
// SUMMODE=1: store column-sums of relu(C) per 128-row m-tile.
// Grid: (N/256, M/128).
// ---------------------------------------------------------------------------
template <typename TC, bool RELU, int SUMMODE>
__global__ __launch_bounds__(256) void mfma_gemm_pipe(
    const bf16_t* __restrict__ A1, const bf16_t* __restrict__ A2, int K1,
    const bf16_t* __restrict__ Wt, TC* __restrict__ C,
    int M, int N, int K)
{
    __shared__ bf16_t As[2][4096];   // 2 x [128][32] = 16KB
    __shared__ bf16_t Bs[2][8192];   // 2 x [256][32] = 32KB

    const int tid = threadIdx.x;
    const int nwg = gridDim.x * gridDim.y;
    const int swz = xcd_swizzle(blockIdx.y * gridDim.x + blockIdx.x, nwg);
    const int mtile = swz / gridDim.x;
    const int ntile = swz - mtile * gridDim.x;
    const int m0 = mtile * 128;
    const int n0 = ntile * 256;

    const int l = tid & 63;
    const int w = tid >> 6;
    const int wr = w >> 1, wc = w & 1;   // wave tile: rows wr*64, cols wc*128
    const int lr = l & 15, lk = l >> 4;

    f32x4 acc[4][8];
#pragma unroll
    for (int m = 0; m < 4; ++m)
#pragma unroll
        for (int n = 0; n < 8; ++n) acc[m][n] = {0.f, 0.f, 0.f, 0.f};

    auto STG = [&](int s, int slot) {
        const int kt = s * 32;
        const bf16_t* ap; int lda, kk;
        if (kt < K1) { ap = A1; lda = K1; kk = kt; }
        else         { ap = A2; lda = K - K1; kk = kt - K1; }
        stage_bf16(ap + (size_t)m0 * lda + kk, lda, As[slot], tid);              // 2
        stage_bf16(Wt + (size_t)n0 * K + kt, K, Bs[slot], tid);                  // 2
        stage_bf16(Wt + (size_t)(n0 + 128) * K + kt, K, Bs[slot] + 4096, tid);   // 2
    };

    const int nt = K >> 5;
    STG(0, 0);

    for (int t = 0; t < nt; ++t) {
        const int cur = t & 1;
        if (t + 1 < nt) {
            STG(t + 1, cur ^ 1);                               // issue next tile
            asm volatile("s_waitcnt vmcnt(6)" ::: "memory");   // tile t landed
        } else {
            asm volatile("s_waitcnt vmcnt(0)" ::: "memory");
        }
        __builtin_amdgcn_s_barrier();          // all waves' tile-t loads in LDS
        __builtin_amdgcn_sched_barrier(0);     // no hoist of ds_reads above

        const bf16_t* as = As[cur];
        const bf16_t* bs = Bs[cur];
        bf16x8 af[4], bfr[8];
#pragma unroll
        for (int m = 0; m < 4; ++m)
            af[m] = *reinterpret_cast<const bf16x8*>(
                as + (wr * 64 + m * 16 + lr) * 32 + lk * 8);
#pragma unroll
        for (int n = 0; n < 8; ++n)
            bfr[n] = *reinterpret_cast<const bf16x8*>(
                bs + (wc * 128 + n * 16 + lr) * 32 + lk * 8);

        __builtin_amdgcn_s_setprio(1);
#pragma unroll
        for (int m = 0; m < 4; ++m)
#pragma unroll
            for (int n = 0; n < 8; ++n)
                acc[m][n] = __builtin_amdgcn_mfma_f32_16x16x32_bf16(
                    af[m], bfr[n], acc[m][n], 0, 0, 0);
        __builtin_amdgcn_s_setprio(0);

        __builtin_amdgcn_sched_barrier(0);     // no sink of reads below
        __builtin_amdgcn_s_barrier();          // reads done -> slot reusable
    }

    if (SUMMODE) {
        __shared__ float red[8][256];
        const int slot = wr * 4 + lk;
#pragma unroll
        for (int n = 0; n < 8; ++n) {
            float cs = 0.f;
#pragma unroll
            for (int m = 0; m < 4; ++m)
#pragma unroll
                for (int r = 0; r < 4; ++r)
                    cs += fmaxf(acc[m][n][r], 0.f);
            red[slot][wc * 128 + n * 16 + lr] = cs;
        }
        __syncthreads();
        {
            float s = 0.f;
#pragma unroll
            for (int s3 = 0; s3 < 8; ++s3) s += red[s3][tid];
            const int batch = mtile & 511, half = mtile >> 9;
            ((float*)C)[(size_t)batch * 1024 + half * 512 + n0 + tid] = s;
        }
        return;
    }

    const int lk4 = lk * 4;
#pragma unroll
    for (int m = 0; m < 4; ++m) {
        const int grow = m0 + wr * 64 + m * 16 + lk4;
#pragma unroll
        for (int n = 0; n < 8; ++n) {
            const int gcol = n0 + wc * 128 + n * 16 + lr;
#pragma unroll
            for (int r = 0; r < 4; ++r) {
                float v = acc[m][n][r];
                if (RELU) v = fmaxf(v, 0.f);
                store_c(C + (size_t)(grow + r) * N + gcol, v);
            }
        }
    }
}

// X fp32 -> bf16 convert: xb[0..HOFFE) = premise, [HOFFE..) = hypothesis.
__global__ __launch_bounds__(256) void xcvt_kernel(
    const float* __restrict__ P, const float* __restrict__ H,
    bf16_t* __restrict__ X)
{
    const size_t NG = 8388608;   // groups of 8 elements (2*HOFFE/8)
    for (size_t g = (size_t)blockIdx.x * 256 + threadIdx.x; g < NG;
         g += (size_t)gridDim.x * 256) {
        size_t i = g * 8;
        const float* s = (i < HOFFE) ? (P + i) : (H + (i - HOFFE));
        float4 f0 = ld4(s), f1 = ld4(s + 4);
        uint4 u = { pk2(f0.x, f0.y), pk2(f0.z, f0.w),
                    pk2(f1.x, f1.y), pk2(f1.z, f1.w) };
        *reinterpret_cast<uint4*>(X + i) = u;
    }
}

// ---------------------------------------------------------------------------
// 2-phase 128x128 MFMA GEMM (scores + path-B fp32-A GEMMs).
// ---------------------------------------------------------------------------
template <typename TA1, typename TC, bool RELU, int SUMMODE>
__global__ __launch_bounds__(256) void mfma_gemm_kernel(
    const TA1* __restrict__ A1, const bf16_t* __restrict__ A2, int K1,
    const bf16_t* __restrict__ Wt, TC* __restrict__ C,
    int M, int N, int K,
    long long saA, long long saB, long long saC)
{
    __shared__ bf16_t As[4096];
    __shared__ bf16_t Bs[4096];
    __shared__ float red[8][128];

    const int tid = threadIdx.x;
    const int z = blockIdx.z;

    const int nwg = gridDim.x * gridDim.y;
    const int swz = xcd_swizzle(blockIdx.y * gridDim.x + blockIdx.x, nwg);
    const int mtile = swz / gridDim.x;
    const int ntile = swz - mtile * gridDim.x;
    const int m0 = mtile * 128;
    const int n0 = ntile * 128;

    const TA1* a1    = A1 + (size_t)z * saA;
    const bf16_t* wt = Wt + (size_t)z * saB;

    const int l = tid & 63;
    const int w = tid >> 6;
    const int wr = w >> 1, wc = w & 1;
    const int lr = l & 15, lk = l >> 4;

    f32x4 acc[4][4];
#pragma unroll
    for (int m = 0; m < 4; ++m)
#pragma unroll
        for (int n = 0; n < 4; ++n) acc[m][n] = {0.f, 0.f, 0.f, 0.f};

    for (int kt = 0; kt < K; kt += 32) {
        if (kt < K1)
            stage_any(a1 + (size_t)m0 * K1 + kt, K1, As, tid);
        else
            stage_bf16(A2 + (size_t)m0 * (K - K1) + (kt - K1), K - K1, As, tid);
        stage_bf16(wt + (size_t)n0 * K + kt, K, Bs, tid);
        __syncthreads();

        bf16x8 af[4], bfr[4];
#pragma unroll
        for (int m = 0; m < 4; ++m)
            af[m] = *reinterpret_cast<const bf16x8*>(
                As + (wr * 64 + m * 16 + lr) * 32 + lk * 8);
#pragma unroll
        for (int n = 0; n < 4; ++n)
            bfr[n] = *reinterpret_cast<const bf16x8*>(
                Bs + (wc * 64 + n * 16 + lr) * 32 + lk * 8);
#pragma unroll
        for (int m = 0; m < 4; ++m)
#pragma unroll
            for (int n = 0; n < 4; ++n)
                acc[m][n] = __builtin_amdgcn_mfma_f32_16x16x32_bf16(
                    af[m], bfr[n], acc[m][n], 0, 0, 0);
        __syncthreads();
    }

    if (SUMMODE) {
        const int slot = wr * 4 + lk;
#pragma unroll
        for (int n = 0; n < 4; ++n) {
            float cs = 0.f;
#pragma unroll
            for (int m = 0; m < 4; ++m)
#pragma unroll
                for (int r = 0; r < 4; ++r)
                    cs += fmaxf(acc[m][n][r], 0.f);
            red[slot][wc * 64 + n * 16 + lr] = cs;
        }
        __syncthreads();
        if (tid < 128) {
            float s = 0.f;
#pragma unroll
            for (int s3 = 0; s3 < 8; ++s3) s += red[s3][tid];
            const int batch = mtile & 511, half = mtile >> 9;
            ((float*)C)[(size_t)batch * 1024 + half * 512 + n0 + tid] = s;
        }
        return;
    }

    TC* cp = C + (size_t)z * saC;
    const int lk4 = lk * 4;
#pragma unroll
    for (int m = 0; m < 4; ++m) {
        const int grow = m0 + wr * 64 + m * 16 + lk4;
#pragma unroll
        for (int n = 0; n < 4; ++n) {
            const int gcol = n0 + wc * 64 + n * 16 + lr;
#pragma unroll
            for (int r = 0; r < 4; ++r) {
                float v = acc[m][n][r];
                if (RELU) v = fmaxf(v, 0.f);
                store_c(cp + (size_t)(grow + r) * N + gcol, v);
            }
        }
    }
}

// ---------------------------------------------------------------------------
// Small-matrix MFMA GEMM: 64x64 tile (aggregate FFN).
// ---------------------------------------------------------------------------
template <bool RELU>
__global__ __launch_bounds__(256) void mfma_gemm_small(
    const float* __restrict__ A, const bf16_t* __restrict__ Wt,
    float* __restrict__ C, int M, int N, int K)
{
    __shared__ bf16_t As[2048];
    __shared__ bf16_t Bs[2048];

    const int tid = threadIdx.x;
    const int nwg = gridDim.x * gridDim.y;
    const int swz = xcd_swizzle(blockIdx.y * gridDim.x + blockIdx.x, nwg);
    const int mtile = swz / gridDim.x;
    const int ntile = swz - mtile * gridDim.x;
    const int m0 = mtile * 64;
    const int n0 = ntile * 64;

    const int l = tid & 63, w = tid >> 6;
    const int wr = w >> 1, wc = w & 1;
    const int lr = l & 15, lk = l >> 4;

    f32x4 acc[2][2];
#pragma unroll
    for (int m = 0; m < 2; ++m)
#pragma unroll
        for (int n = 0; n < 2; ++n) acc[m][n] = {0.f, 0.f, 0.f, 0.f};

    const int arow = tid >> 2;
    const int aseg = (tid & 3) * 8;

    for (int kt = 0; kt < K; kt += 32) {
        const float* s = A + (size_t)(m0 + arow) * K + kt + aseg;
        float4 f0 = ld4(s), f1 = ld4(s + 4);
        uint4 u = { pk2(f0.x, f0.y), pk2(f0.z, f0.w),
                    pk2(f1.x, f1.y), pk2(f1.z, f1.w) };
        __syncthreads();
        *reinterpret_cast<uint4*>(As + arow * 32 + aseg) = u;
        {
            const int row = w * 16 + (l >> 2);
            const int ce  = (l & 3) * 8;
            gload_lds16(Wt + (size_t)(n0 + row) * K + kt + ce, Bs + w * 512);
        }
        __syncthreads();

        bf16x8 af[2], bfr[2];
#pragma unroll
        for (int m = 0; m < 2; ++m)
            af[m] = *reinterpret_cast<const bf16x8*>(
                As + (wr * 32 + m * 16 + lr) * 32 + lk * 8);
#pragma unroll
        for (int n = 0; n < 2; ++n)
            bfr[n] = *reinterpret_cast<const bf16x8*>(
                Bs + (wc * 32 + n * 16 + lr) * 32 + lk * 8);
#pragma unroll
        for (int m = 0; m < 2; ++m)
#pragma unroll
            for (int n = 0; n < 2; ++n)
                acc[m][n] = __builtin_amdgcn_mfma_f32_16x16x32_bf16(
                    af[m], bfr[n], acc[m][n], 0, 0, 0);
    }

    const int lk4 = lk * 4;
#pragma unroll
    for (int m = 0; m < 2; ++m) {
        const int grow = m0 + wr * 32 + m * 16 + lk4;
#pragma unroll
        for (int n = 0; n < 2; ++n) {
            const int gcol = n0 + wc * 32 + n * 16 + lr;
#pragma unroll
            for (int r = 0; r < 4; ++r) {
                float v = acc[m][n][r];
                if (RELU) v = fmaxf(v, 0.f);
                C[(size_t)(grow + r) * N + gcol] = v;
            }
        }
    }
}

// ---------------------------------------------------------------------------
// Fused softmax + alignment via MFMA. grid (512 batches, 2 modes).
// TS = source element type (bf16 xb on path A, fp32 raw inputs on path B).
// ---------------------------------------------------------------------------
__device__ inline unsigned pkpair(const float* s, int k, int col) {
    return pk2(s[(size_t)k * 512 + col], s[(size_t)(k + 1) * 512 + col]);
}
__device__ inline unsigned pkpair(const bf16_t* s, int k, int col) {
    return ((unsigned)s[(size_t)(k + 1) * 512 + col] << 16)
         | (unsigned)s[(size_t)k * 512 + col];
}

template <typename TS>
__global__ __launch_bounds__(256) void align_mfma_kernel(
    const float* __restrict__ S, const TS* __restrict__ prem,
    const TS* __restrict__ hyp, bf16_t* __restrict__ Out)
{
    const int b = blockIdx.x;
    const int mode = blockIdx.y;
    __shared__ bf16_t E[128][136];
    __shared__ bf16_t Bs[128][36];

    const int tid = threadIdx.x;
    const float* sp  = S + (size_t)b * 16384;
    const TS* src = (mode == 0 ? hyp : prem) + (size_t)b * 65536;
    bf16_t* outp = Out + (size_t)mode * HOFFE + (size_t)b * 65536;

    if (mode == 0) {
        const int r = tid >> 1, seg = (tid & 1) * 64;
#pragma unroll
        for (int i = 0; i < 16; ++i) {
            float4 v = ld4(sp + (size_t)r * 128 + seg + i * 4);
            uint2 u = { pk2(v.x, v.y), pk2(v.z, v.w) };
            *reinterpret_cast<uint2*>(&E[r][seg + i * 4]) = u;
        }
    } else {
#pragma unroll
        for (int it = 0; it < 16; ++it) {
            int i = tid + it * 256;
            int c = i >> 5, r4 = (i & 31) << 2;
            float4 v = ld4(sp + (size_t)c * 128 + r4);
            E[r4 + 0][c] = f2bf(v.x); E[r4 + 1][c] = f2bf(v.y);
            E[r4 + 2][c] = f2bf(v.z); E[r4 + 3][c] = f2bf(v.w);
        }
    }
    __syncthreads();

    {
        const int r = tid >> 1, seg = (tid & 1) * 64;
        float m = -1e30f;
#pragma unroll
        for (int i = 0; i < 32; ++i) {
            unsigned u = *reinterpret_cast<const unsigned*>(&E[r][seg + i * 2]);
            m = fmaxf(m, fmaxf(bf2f((bf16_t)(u & 0xffff)), bf2f((bf16_t)(u >> 16))));
        }
        m = fmaxf(m, __shfl_xor(m, 1));
        float s = 0.f;
#pragma unroll
        for (int i = 0; i < 32; ++i) {
            unsigned u = *reinterpret_cast<const unsigned*>(&E[r][seg + i * 2]);
            s += __expf(bf2f((bf16_t)(u & 0xffff)) - m)
               + __expf(bf2f((bf16_t)(u >> 16)) - m);
        }
        s += __shfl_xor(s, 1);
        const float inv = 1.f / s;
#pragma unroll
        for (int i = 0; i < 32; ++i) {
            unsigned u = *reinterpret_cast<const unsigned*>(&E[r][seg + i * 2]);
            float p0 = __expf(bf2f((bf16_t)(u & 0xffff)) - m) * inv;
            float p1 = __expf(bf2f((bf16_t)(u >> 16)) - m) * inv;
            *reinterpret_cast<unsigned*>(&E[r][seg + i * 2]) = pk2(p0, p1);
        }
    }

    const int l = tid & 63, w = tid >> 6;
    const int wr = w >> 1, wc = w & 1;
    const int lr = l & 15, lk = l >> 4;
    const int sn  = tid & 127;
    const int skh = tid >> 7;

    for (int nt = 0; nt < 4; ++nt) {
        const int n0 = nt * 128;
        f32x4 acc[4][4];
#pragma unroll
        for (int m = 0; m < 4; ++m)
#pragma unroll
            for (int n = 0; n < 4; ++n) acc[m][n] = {0.f, 0.f, 0.f, 0.f};

        for (int kt = 0; kt < 4; ++kt) {
            const int k0 = kt * 32;
            unsigned pkv[8];
#pragma unroll
            for (int j = 0; j < 8; ++j) {
                const int k = k0 + (skh * 8 + j) * 2;
                pkv[j] = pkpair(src, k, n0 + sn);
            }
            __syncthreads();
#pragma unroll
            for (int j = 0; j < 8; ++j)
                *reinterpret_cast<unsigned*>(&Bs[sn][(skh * 8 + j) * 2]) = pkv[j];
            __syncthreads();

            bf16x8 af[4], bfr[4];
#pragma unroll
            for (int m = 0; m < 4; ++m)
                af[m] = *reinterpret_cast<const bf16x8*>(
                    &E[wr * 64 + m * 16 + lr][k0 + lk * 8]);
#pragma unroll
            for (int n = 0; n < 4; ++n) {
                const bf16_t* bp = &Bs[wc * 64 + n * 16 + lr][lk * 8];
                union { bf16x8 v; uint2 u[2]; } t2;
                t2.u[0] = *reinterpret_cast<const uint2*>(bp);
                t2.u[1] = *reinterpret_cast<const uint2*>(bp + 4);
                bfr[n] = t2.v;
            }
#pragma unroll
            for (int m = 0; m < 4; ++m)
#pragma unroll
                for (int n = 0; n < 4; ++n)
                    acc[m][n] = __builtin_amdgcn_mfma_f32_16x16x32_bf16(
                        af[m], bfr[n], acc[m][n], 0, 0, 0);
        }

        const int lk4 = lk * 4;
#pragma unroll
        for (int m = 0; m < 4; ++m) {
            const int grow = wr * 64 + m * 16 + lk4;
#pragma unroll
            for (int n = 0; n < 4; ++n) {
                const int gcol = n0 + wc * 64 + n * 16 + lr;
#pragma unroll
                for (int r = 0; r < 4; ++r)
                    outp[(size_t)(grow + r) * 512 + gcol] = f2bf(acc[m][n][r]);
            }
        }
        __syncthreads();
    }
}

// Weight convert+transpose: W fp32 [K,N] -> Wt bf16 [N,K]. Grid (K/32, N/32).
__global__ __launch_bounds__(256) void wcvt_transpose(
    const float* __restrict__ W, bf16_t* __restrict__ Wt, int K, int N)
{
    __shared__ float t[32][33];
    const int k0 = blockIdx.x * 32, n0 = blockIdx.y * 32;
    const int r = threadIdx.x >> 3;
    const int c = (threadIdx.x & 7) * 4;
    float4 v = ld4(W + (size_t)(k0 + r) * N + n0 + c);
    t[r][c] = v.x; t[r][c + 1] = v.y; t[r][c + 2] = v.z; t[r][c + 3] = v.w;
    __syncthreads();
    ushort4 o;
    o.x = f2bf(t[c + 0][r]); o.y = f2bf(t[c + 1][r]);
    o.z = f2bf(t[c + 2][r]); o.w = f2bf(t[c + 3][r]);
    *reinterpret_cast<ushort4*>(Wt + (size_t)(n0 + r) * K + k0 + c) = o;
}

// ===========================================================================
// Round-2 kernels (VALU path; fallback only)
// ===========================================================================

template <typename TA1, typename TA2, typename TC>
__global__ __launch_bounds__(256) void gemm_relu_kernel(
    const TA1* __restrict__ A1, const TA2* __restrict__ A2, int K1,
    const float* __restrict__ W, TC* __restrict__ C,
    int M, int N, int K)
{
    __shared__ __align__(16) float As[8][132];
    __shared__ __align__(16) float Bs[8][132];

    const int tid = threadIdx.x;
    const int tx = tid & 15;
    const int ty = tid >> 4;
    const int m0 = blockIdx.y * 128;
    const int n0 = blockIdx.x * 128;

    const int arow = tid >> 1;
    const int apart = tid & 1;
    const int brow = tid >> 5;
    const int bcol = (tid & 31) << 2;

    float acc[8][8];
#pragma unroll
    for (int i = 0; i < 8; ++i)
#pragma unroll
        for (int j = 0; j < 8; ++j) acc[i][j] = 0.f;

    for (int kt = 0; kt < K; kt += 8) {
        float4 av;
        if (kt < K1)
            av = ld4(A1 + (size_t)(m0 + arow) * K1 + kt + apart * 4);
        else
            av = ld4(A2 + (size_t)(m0 + arow) * (K - K1) + (kt - K1) + apart * 4);
        float4 bv = ld4(W + (size_t)(kt + brow) * N + n0 + bcol);

        __syncthreads();
        As[apart * 4 + 0][arow] = av.x;
        As[apart * 4 + 1][arow] = av.y;
        As[apart * 4 + 2][arow] = av.z;
        As[apart * 4 + 3][arow] = av.w;
        *reinterpret_cast<float4*>(&Bs[brow][bcol]) = bv;
        __syncthreads();

#pragma unroll
        for (int k = 0; k < 8; ++k) {
            float4 a0 = *reinterpret_cast<const float4*>(&As[k][ty * 8]);
            float4 a1 = *reinterpret_cast<const float4*>(&As[k][ty * 8 + 4]);
            float4 b0 = *reinterpret_cast<const float4*>(&Bs[k][tx * 8]);
            float4 b1 = *reinterpret_cast<const float4*>(&Bs[k][tx * 8 + 4]);
            float a[8] = {a0.x, a0.y, a0.z, a0.w, a1.x, a1.y, a1.z, a1.w};
            float b[8] = {b0.x, b0.y, b0.z, b0.w, b1.x, b1.y, b1.z, b1.w};
#pragma unroll
            for (int i = 0; i < 8; ++i)
#pragma unroll
                for (int j = 0; j < 8; ++j)
                    acc[i][j] = fmaf(a[i], b[j], acc[i][j]);
        }
    }

#pragma unroll
    for (int i = 0; i < 8; ++i) {
        float4 v0, v1;
        v0.x = fmaxf(acc[i][0], 0.f); v0.y = fmaxf(acc[i][1], 0.f);
        v0.z = fmaxf(acc[i][2], 0.f); v0.w = fmaxf(acc[i][3], 0.f);
        v1.x = fmaxf(acc[i][4], 0.f); v1.y = fmaxf(acc[i][5], 0.f);
        v1.z = fmaxf(acc[i][6], 0.f); v1.w = fmaxf(acc[i][7], 0.f);
        size_t off = (size_t)(m0 + ty * 8 + i) * N + n0 + tx * 8;
        st4(C + off, v0);
        st4(C + off + 4, v1);
    }
}

__global__ __launch_bounds__(256) void scores_valu_kernel(
    const bf16_t* __restrict__ Pp, const bf16_t* __restrict__ Ph,
    float* __restrict__ S)
{
    const int b = blockIdx.x;
    __shared__ __align__(16) float Ap[16][132];
    __shared__ __align__(16) float Bh[16][132];

    const int tid = threadIdx.x;
    const int tx = tid & 15, ty = tid >> 4;
    const bf16_t* pa = Pp + (size_t)b * 65536;
    const bf16_t* pb = Ph + (size_t)b * 65536;
    const int lrow = tid >> 2;
    const int lq = tid & 3;

    float acc[8][8];
#pragma unroll
    for (int i = 0; i < 8; ++i)
#pragma unroll
        for (int j = 0; j < 8; ++j) acc[i][j] = 0.f;

    for (int kt = 0; kt < 512; kt += 16) {
        __syncthreads();
#pragma unroll
        for (int h = 0; h < 2; ++h) {
            int row = lrow + h * 64;
            float4 v = ld4(pa + (size_t)row * 512 + kt + lq * 4);
            Ap[lq * 4 + 0][row] = v.x; Ap[lq * 4 + 1][row] = v.y;
            Ap[lq * 4 + 2][row] = v.z; Ap[lq * 4 + 3][row] = v.w;
            float4 w2 = ld4(pb + (size_t)row * 512 + kt + lq * 4);
            Bh[lq * 4 + 0][row] = w2.x; Bh[lq * 4 + 1][row] = w2.y;
            Bh[lq * 4 + 2][row] = w2.z; Bh[lq * 4 + 3][row] = w2.w;
        }
        __syncthreads();
#pragma unroll
        for (int k = 0; k < 16; ++k) {
            float4 a0 = *reinterpret_cast<const float4*>(&Ap[k][ty * 8]);
            float4 a1 = *reinterpret_cast<const float4*>(&Ap[k][ty * 8 + 4]);
            float4 b0 = *reinterpret_cast<const float4*>(&Bh[k][tx * 8]);
            float4 b1 = *reinterpret_cast<const float4*>(&Bh[k][tx * 8 + 4]);
            float a[8] = {a0.x, a0.y, a0.z, a0.w, a1.x, a1.y, a1.z, a1.w};
            float b[8] = {b0.x, b0.y, b0.z, b0.w, b1.x, b1.y, b1.z, b1.w};
#pragma unroll
            for (int i = 0; i < 8; ++i)
#pragma unroll
                for (int j = 0; j < 8; ++j)
                    acc[i][j] = fmaf(a[i], b[j], acc[i][j]);
        }
    }

    float* sp = S + (size_t)b * 16384;
#pragma unroll
    for (int i = 0; i < 8; ++i) {
        float4 v0 = {acc[i][0], acc[i][1], acc[i][2], acc[i][3]};
        float4 v1 = {acc[i][4], acc[i][5], acc[i][6], acc[i][7]};
        size_t off = (size_t)(ty * 8 + i) * 128 + tx * 8;
        *reinterpret_cast<float4*>(sp + off)     = v0;
        *reinterpret_cast<float4*>(sp + off + 4) = v1;
    }
}

template <int MODE>
__global__ __launch_bounds__(256) void align_kernel(
    const float* __restrict__ S, const float* __restrict__ Src,
    bf16_t* __restrict__ Out)
{
    const int b = blockIdx.x;
    __shared__ __align__(16) float E[64][132];
    __shared__ __align__(16) float Hs[16][132];
    __shared__ float statm[64], stati[64];

    const int tid = threadIdx.x;
    const int ty = tid >> 5;
    const int tx = tid & 31;
    const float* sp = S + (size_t)b * 16384;
    const float* src = Src + (size_t)b * 65536;
    bf16_t* outp = Out + (size_t)b * 65536;

    for (int h0 = 0; h0 < 128; h0 += 64) {
        __syncthreads();
        if (MODE == 0) {
            for (int idx = tid; idx < 2048; idx += 256) {
                int r = idx >> 5, c4 = (idx & 31) << 2;
                float4 v = ld4(sp + (size_t)(h0 + r) * 128 + c4);
                E[r][c4 + 0] = v.x; E[r][c4 + 1] = v.y;
                E[r][c4 + 2] = v.z; E[r][c4 + 3] = v.w;
            }
        } else {
            for (int idx = tid; idx < 2048; idx += 256) {
                int c = idx >> 4, r4 = (idx & 15) << 2;
                float4 v = ld4(sp + (size_t)c * 128 + h0 + r4);
                E[r4 + 0][c] = v.x; E[r4 + 1][c] = v.y;
                E[r4 + 2][c] = v.z; E[r4 + 3][c] = v.w;
            }
        }
        __syncthreads();

        if (tid < 64) {
            float m = -1e30f;
            for (int c = 0; c < 128; ++c) m = fmaxf(m, E[tid][c]);
            float s = 0.f;
            for (int c = 0; c < 128; ++c) s += __expf(E[tid][c] - m);
            statm[tid] = m;
            stati[tid] = 1.f / s;
        }
        __syncthreads();

        for (int idx = tid; idx < 8192; idx += 256) {
            int r = idx >> 7, c = idx & 127;
            E[r][c] = __expf(E[r][c] - statm[r]) * stati[r];
        }

        for (int dc = 0; dc < 4; ++dc) {
            float acc[8][4];
#pragma unroll
            for (int i = 0; i < 8; ++i)
#pragma unroll
                for (int j = 0; j < 4; ++j) acc[i][j] = 0.f;

            for (int ct = 0; ct < 8; ++ct) {
                __syncthreads();
                for (int idx = tid; idx < 512; idx += 256) {
                    int r = idx >> 5, c4 = (idx & 31) << 2;
                    float4 v = ld4(src + (size_t)(ct * 16 + r) * 512 + dc * 128 + c4);
                    *reinterpret_cast<float4*>(&Hs[r][c4]) = v;
                }
                __syncthreads();
#pragma unroll
                for (int k = 0; k < 16; ++k) {
                    int c = ct * 16 + k;
                    float a[8];
#pragma unroll
                    for (int i = 0; i < 8; ++i) a[i] = E[ty * 8 + i][c];
                    float4 b4 = *reinterpret_cast<const float4*>(&Hs[k][tx * 4]);
                    float bb[4] = {b4.x, b4.y, b4.z, b4.w};
#pragma unroll
                    for (int i = 0; i < 8; ++i)
#pragma unroll
                        for (int j = 0; j < 4; ++j)
                            acc[i][j] = fmaf(a[i], bb[j], acc[i][j]);
                }
            }
#pragma unroll
            for (int i = 0; i < 8; ++i) {
                float4 v = {acc[i][0], acc[i][1], acc[i][2], acc[i][3]};
                st4(outp + (size_t)(h0 + ty * 8 + i) * 512 + dc * 128 + tx * 4, v);
            }
        }
    }
}

__global__ __launch_bounds__(128) void seqsum_kernel(
    const bf16_t* __restrict__ Cmp, float* __restrict__ Agg)
{
    const int b = blockIdx.x;
    const int half = blockIdx.y;
    const bf16_t* base = Cmp + (size_t)half * HOFFE + (size_t)b * 65536 + threadIdx.x * 4;
    float4 s = {0.f, 0.f, 0.f, 0.f};
    for (int r = 0; r < 128; ++r) {
        ushort4 u = *reinterpret_cast<const ushort4*>(base + (size_t)r * 512);
        s.x += bf2f(u.x); s.y += bf2f(u.y); s.z += bf2f(u.z); s.w += bf2f(u.w);
    }
    *reinterpret_cast<float4*>(Agg + (size_t)b * 1024 + half * 512 + threadIdx.x * 4) = s;
}

__global__ __launch_bounds__(64) void scorer_kernel(
    const float* __restrict__ H, const float* __restrict__ Wsc,
    float* __restrict__ Out)
{
    const int row = blockIdx.x;
    const int l = threadIdx.x;
    float a0 = 0.f, a1 = 0.f;
    for (int h = l; h < 512; h += 64) {
        float v = H[(size_t)row * 512 + h];
        a0 = fmaf(v, Wsc[h * 2 + 0], a0);
        a1 = fmaf(v, Wsc[h * 2 + 1], a1);
    }
#pragma unroll
    for (int off = 32; off > 0; off >>= 1) {
        a0 += __shfl_down(a0, off);
        a1 += __shfl_down(a1, off);
    }
    if (l == 0) {
        float m = fmaxf(a0, a1);
        float e0 = __expf(a0 - m), e1 = __expf(a1 - m);
        float inv = 1.f / (e0 + e1);
        Out[row * 2 + 0] = e0 * inv;
        Out[row * 2 + 1] = e1 * inv;
    }
}

// ===========================================================================
extern "C" void kernel_launch(void* const* d_in, const int* in_sizes, int n_in,
                              void* d_out, int out_size, void* d_ws, size_t ws_size,
                              hipStream_t stream)
{
    const float* premise    = (const float*)d_in[0];
    const float* hypothesis = (const float*)d_in[1];
    const float* aw0 = (const float*)d_in[2];
    const float* aw1 = (const float*)d_in[3];
    const float* cw0 = (const float*)d_in[4];
    const float* cw1 = (const float*)d_in[5];
    const float* gw0 = (const float*)d_in[6];
    const float* gw1 = (const float*)d_in[7];
    const float* wsc = (const float*)d_in[8];
    float* out = (float*)d_out;

    char* ws = (char*)d_ws;
    dim3 blk(256);

    const size_t MB128 = 134217728ull;
    const size_t NEED_A = 3 * MB128 + 4194304 + 4194304;
    const size_t NEED_B = 2 * MB128 + 4194304 + 4194304;

    if (ws_size >= NEED_A) {
        // ---------------- path A: full pipeline, all-bf16 big GEMMs --------
        bf16_t* xb = (bf16_t*)ws;                       // [131072,512] bf16
        bf16_t* r0 = (bf16_t*)(ws + MB128);             // T1 -> (scores) -> C1
        bf16_t* r1 = (bf16_t*)(ws + 2 * MB128);         // proj -> align
        float* scoresF = (float*)(ws + MB128);          // overlays r0 (T1 dead)
        const size_t WOFF = 3 * MB128;
        bf16_t* awt0 = (bf16_t*)(ws + WOFF);
        bf16_t* awt1 = awt0 + 262144;
        bf16_t* cwt0 = awt1 + 262144;
        bf16_t* cwt1 = cwt0 + 524288;
        bf16_t* gwt0 = cwt1 + 262144;
        bf16_t* gwt1 = gwt0 + 524288;
        float* aggF  = (float*)(ws + WOFF + 4194304);
        float* hid1F = aggF + 524288;
        float* hid2F = hid1F + 262144;

        xcvt_kernel<<<2048, blk, 0, stream>>>(premise, hypothesis, xb);
        wcvt_transpose<<<dim3(16, 16), blk, 0, stream>>>(aw0, awt0, 512, 512);
        wcvt_transpose<<<dim3(16, 16), blk, 0, stream>>>(aw1, awt1, 512, 512);
        wcvt_transpose<<<dim3(32, 16), blk, 0, stream>>>(cw0, cwt0, 1024, 512);
        wcvt_transpose<<<dim3(16, 16), blk, 0, stream>>>(cw1, cwt1, 512, 512);
        wcvt_transpose<<<dim3(32, 16), blk, 0, stream>>>(gw0, gwt0, 1024, 512);
        wcvt_transpose<<<dim3(16, 16), blk, 0, stream>>>(gw1, gwt1, 512, 512);

        // 1. Attend L1 (both sentences): T1 = relu(xb @ aw0) -> r0
        mfma_gemm_pipe<bf16_t, true, 0><<<dim3(2, 1024), blk, 0, stream>>>(
            xb, xb, 512, awt0, r0, 131072, 512, 512);
        // 2. Attend L2: proj = relu(T1 @ aw1) -> r1
        mfma_gemm_pipe<bf16_t, true, 0><<<dim3(2, 1024), blk, 0, stream>>>(
            r0, r0, 512, awt1, r1, 131072, 512, 512);
        // 3. scores[b] = proj_p[b] @ proj_h[b]^T -> scoresF (overlays r0)
        mfma_gemm_kernel<bf16_t, float, false, 0><<<dim3(1, 1, 512), blk, 0, stream>>>(
            r1, nullptr, 512, r1 + HOFFE, scoresF, 128, 128, 512,
            65536LL, 65536LL, 16384LL);
        // 4. alignments -> r1 (overwrites proj); src = bf16 xb
        align_mfma_kernel<bf16_t><<<dim3(512, 2), blk, 0, stream>>>(
            scoresF, xb, xb + HOFFE, r1);
        // 5. Compare L1: relu([xb | align] @ cw0) -> r0
        mfma_gemm_pipe<bf16_t, true, 0><<<dim3(2, 1024), blk, 0, stream>>>(
            xb, r1, 512, cwt0, r0, 131072, 512, 1024);
        // 6. Compare L2 fused seq-sum -> aggregated
        mfma_gemm_pipe<float, true, 1><<<dim3(2, 1024), blk, 0, stream>>>(
            r0, r0, 512, cwt1, aggF, 131072, 512, 512);
        // 7. Aggregate FFN + scorer
        mfma_gemm_small<true><<<dim3(8, 8), blk, 0, stream>>>(
            aggF, gwt0, hid1F, 512, 512, 1024);
        mfma_gemm_small<true><<<dim3(8, 8), blk, 0, stream>>>(
            hid1F, gwt1, hid2F, 512, 512, 512);
        scorer_kernel<<<512, 64, 0, stream>>>(hid2F, wsc, out);
    } else if (ws_size >= NEED_B) {
        // ---------------- path B: round-6 layout; pipe for bf16-A GEMMs ----
        bf16_t* r0 = (bf16_t*)ws;
        bf16_t* r1 = (bf16_t*)(ws + MB128);
        float* scoresF = (float*)ws;
        const size_t WOFF = 2 * MB128;
        bf16_t* awt0 = (bf16_t*)(ws + WOFF);
        bf16_t* awt1 = awt0 + 262144;
        bf16_t* cwt0 = awt1 + 262144;
        bf16_t* cwt1 = cwt0 + 524288;
        bf16_t* gwt0 = cwt1 + 262144;
        bf16_t* gwt1 = gwt0 + 524288;
        float* aggF  = (float*)(ws + WOFF + 4194304);
        float* hid1F = aggF + 524288;
        float* hid2F = hid1F + 262144;

        wcvt_transpose<<<dim3(16, 16), blk, 0, stream>>>(aw0, awt0, 512, 512);
        wcvt_transpose<<<dim3(16, 16), blk, 0, stream>>>(aw1, awt1, 512, 512);
        wcvt_transpose<<<dim3(32, 16), blk, 0, stream>>>(cw0, cwt0, 1024, 512);
        wcvt_transpose<<<dim3(16, 16), blk, 0, stream>>>(cw1, cwt1, 512, 512);
        wcvt_transpose<<<dim3(32, 16), blk, 0, stream>>>(gw0, gwt0, 1024, 512);
        wcvt_transpose<<<dim3(16, 16), blk, 0, stream>>>(gw1, gwt1, 512, 512);

        mfma_gemm_kernel<float, bf16_t, true, 0><<<dim3(4, 512, 1), blk, 0, stream>>>(
            premise, nullptr, 512, awt0, r0, 65536, 512, 512, 0, 0, 0);
        mfma_gemm_kernel<float, bf16_t, true, 0><<<dim3(4, 512, 1), blk, 0, stream>>>(
            hypothesis, nullptr, 512, awt0, r0 + HOFFE, 65536, 512, 512, 0, 0, 0);
        mfma_gemm_pipe<bf16_t, true, 0><<<dim3(2, 1024), blk, 0, stream>>>(
            r0, r0, 512, awt1, r1, 131072, 512, 512);
        mfma_gemm_kernel<bf16_t, float, false, 0><<<dim3(1, 1, 512), blk, 0, stream>>>(
            r1, nullptr, 512, r1 + HOFFE, scoresF, 128, 128, 512,
            65536LL, 65536LL, 16384LL);
        align_mfma_kernel<float><<<dim3(512, 2), blk, 0, stream>>>(
            scoresF, premise, hypothesis, r1);
        mfma_gemm_kernel<float, bf16_t, true, 0><<<dim3(4, 512, 1), blk, 0, stream>>>(
            premise, r1, 512, cwt0, r0, 65536, 512, 1024, 0, 0, 0);
        mfma_gemm_kernel<float, bf16_t, true, 0><<<dim3(4, 512, 1), blk, 0, stream>>>(
            hypothesis, r1 + HOFFE, 512, cwt0, r0 + HOFFE, 65536, 512, 1024, 0, 0, 0);
        mfma_gemm_pipe<float, true, 1><<<dim3(2, 1024), blk, 0, stream>>>(
            r0, r0, 512, cwt1, aggF, 131072, 512, 512);
        mfma_gemm_small<true><<<dim3(8, 8), blk, 0, stream>>>(
            aggF, gwt0, hid1F, 512, 512, 1024);
        mfma_gemm_small<true><<<dim3(8, 8), blk, 0, stream>>>(
            hid1F, gwt1, hid2F, 512, 512, 512);
        scorer_kernel<<<512, 64, 0, stream>>>(hid2F, wsc, out);
    } else {
        // ---------------- path C: round-2 VALU fallback (complete) ---------
        bf16_t* r0 = (bf16_t*)ws;
        bf16_t* r1 = (bf16_t*)(ws + MB128);
        float* scoresF = (float*)ws;
        float* aggF  = (float*)ws;
        float* hid1F = (float*)(ws + (size_t)4194304);
        float* hid2F = (float*)(ws + (size_t)8388608);
        gemm_relu_kernel<float, bf16_t, bf16_t><<<dim3(4, 512), blk, 0, stream>>>(
            premise, nullptr, 512, aw0, r0, 65536, 512, 512);
        gemm_relu_kernel<float, bf16_t, bf16_t><<<dim3(4, 512), blk, 0, stream>>>(
            hypothesis, nullptr, 512, aw0, r0 + HOFFE, 65536, 512, 512);
        gemm_relu_kernel<bf16_t, bf16_t, bf16_t><<<dim3(4, 1024), blk, 0, stream>>>(
            r0, nullptr, 512, aw1, r1, 131072, 512, 512);
        scores_valu_kernel<<<512, blk, 0, stream>>>(r1, r1 + HOFFE, scoresF);
        align_kernel<0><<<512, blk, 0, stream>>>(scoresF, hypothesis, r1);
        align_kernel<1><<<512, blk, 0, stream>>>(scoresF, premise, r1 + HOFFE);
        gemm_relu_kernel<float, bf16_t, bf16_t><<<dim3(4, 512), blk, 0, stream>>>(
            premise, r1, 512, cw0, r0, 65536, 512, 1024);
        gemm_relu_kernel<float, bf16_t, bf16_t><<<dim3(4, 512), blk, 0, stream>>>(
            hypothesis, r1 + HOFFE, 512, cw0, r0 + HOFFE, 65536, 512, 1024);
        gemm_relu_kernel<bf16_t, bf16_t, bf16_t><<<dim3(4, 1024), blk, 0, stream>>>(
            r0, nullptr, 512, cw1, r1, 131072, 512, 512);
        seqsum_kernel<<<dim3(512, 2), 128, 0, stream>>>(r1, aggF);
        gemm_relu_kernel<float, bf16_t, float><<<dim3(4, 4), blk, 0, stream>>>(
            aggF, nullptr, 1024, gw0, hid1F, 512, 512, 1024);
        gemm_relu_kernel<float, bf16_t, float><<<dim3(4, 4), blk, 0, stream>>>(
            hid1F, nullptr, 512, gw1, hid2F, 512, 512, 512);
        scorer_kernel<<<512, 64, 0, stream>>>(hid2F, wsc, out);
    }
}

// Round 11
// 764.640 us; speedup vs baseline: 1.3879x; 1.3879x over previous
//
#include <hip/hip_runtime.h>
#include <cstddef>

// Decomposable Attention Entailment forward. B=512, P=Q=128, D=H=512.
// Round 11: round-9's 128x256 / 3-buffer pipe + __launch_bounds__(256,2).
// Round-9/10 post-mortem: acc[4][8] (128 unified regs) + 136 VGPR = ~264
// regs/wave -> 1 wave/SIMD (occupancy 11.4%) regardless of LDS. Cap the
// allocator at 256 regs (2 waves/SIMD) so the wide tile's better
// FLOP-per-LDS-read (0.375) actually gets latency cover. 72KB x 2 = 144KB
// LDS fits 2 blocks/CU.

typedef unsigned short bf16_t;
typedef __attribute__((ext_vector_type(8))) short bf16x8;   // 8 bf16 = 4 VGPRs
typedef __attribute__((ext_vector_type(4))) float f32x4;

#define HOFFE ((size_t)33554432)   // elements per sentence tensor (512*128*512)

__device__ inline float bf2f(bf16_t u) {
    return __uint_as_float((unsigned)u << 16);
}
__device__ inline bf16_t f2bf(float f) {
    unsigned v = __float_as_uint(f);
    v += 0x7FFFu + ((v >> 16) & 1u);       // round-to-nearest-even
    return (bf16_t)(v >> 16);
}
__device__ inline unsigned pk2(float a, float b) {   // low = a, high = b
    return ((unsigned)f2bf(b) << 16) | (unsigned)f2bf(a);
}

__device__ inline float4 ld4(const float* p) {
    return *reinterpret_cast<const float4*>(p);
}
__device__ inline float4 ld4(const bf16_t* p) {
    ushort4 u = *reinterpret_cast<const ushort4*>(p);
    float4 f;
    f.x = bf2f(u.x); f.y = bf2f(u.y); f.z = bf2f(u.z); f.w = bf2f(u.w);
    return f;
}
__device__ inline void st4(float* p, float4 v) {
    *reinterpret_cast<float4*>(p) = v;
}
__device__ inline void st4(bf16_t* p, float4 v) {
    ushort4 u;
    u.x = f2bf(v.x); u.y = f2bf(v.y); u.z = f2bf(v.z); u.w = f2bf(v.w);
    *reinterpret_cast<ushort4*>(p) = u;
}

// Bijective XCD swizzle (learn_hip m204).
__device__ inline int xcd_swizzle(int orig, int nwg) {
    const int q = nwg >> 3, r = nwg & 7;
    const int xcd = orig & 7, idx = orig >> 3;
    return (xcd < r ? xcd * (q + 1) : r * (q + 1) + (xcd - r) * q) + idx;
}

// ===========================================================================
// MFMA GEMM machinery
// ===========================================================================

__device__ inline void gload_lds16(const bf16_t* g, bf16_t* l) {
    __builtin_amdgcn_global_load_lds(
        (const __attribute__((address_space(1))) unsigned int*)g,
        (__attribute__((address_space(3))) unsigned int*)l, 16, 0, 0);
}

// Stage a [128 x 32] bf16 tile into 8KB LDS ([row][32] linear). 2 issues/thread.
__device__ inline void stage_bf16(const bf16_t* __restrict__ src, int ld,
                                  bf16_t* dst, int tid) {
    const int l = tid & 63, w = tid >> 6;
#pragma unroll
    for (int i = 0; i < 2; ++i) {
        const int chunk = w * 2 + i;             // 0..7 (1KB chunks)
        const int row = chunk * 16 + (l >> 2);   // 0..127
        const int ce  = (l & 3) * 8;             // element col offset
        gload_lds16(src + (size_t)row * ld + ce, dst + chunk * 512);
    }
}

__device__ inline void stage_f32(const float* __restrict__ src, int ld,
                                 bf16_t* dst, int tid) {
    const int row = tid >> 1;
    const int seg = (tid & 1) * 16;
    const float* s = src + (size_t)row * ld + seg;
    float4 f0 = ld4(s), f1 = ld4(s + 4), f2_ = ld4(s + 8), f3 = ld4(s + 12);
    uint4 u0 = { pk2(f0.x, f0.y), pk2(f0.z, f0.w), pk2(f1.x, f1.y), pk2(f1.z, f1.w) };
    uint4 u1 = { pk2(f2_.x, f2_.y), pk2(f2_.z, f2_.w), pk2(f3.x, f3.y), pk2(f3.z, f3.w) };
    *reinterpret_cast<uint4*>(dst + row * 32 + seg)     = u0;
    *reinterpret_cast<uint4*>(dst + row * 32 + seg + 8) = u1;
}

__device__ inline void stage_any(const bf16_t* src, int ld, bf16_t* dst, int tid) {
    stage_bf16(src, ld, dst, tid);
}
__device__ inline void stage_any(const float* src, int ld, bf16_t* dst, int tid) {
    stage_f32(src, ld, dst, tid);
}

__device__ inline void store_c(float* p, float v)  { *p = v; }
__device__ inline void store_c(bf16_t* p, float v) { *p = f2bf(v); }

// ---------------------------------------------------------------------------
// Pipelined MFMA GEMM, 128(M) x 256(N) block tile, wave tile 64x128.
// All-bf16 operands: C = relu?([A1 | A2] @ Wt^T). 3 LDS buffer sets (72KB);
// staging runs 2 K-tiles ahead (6 gload_lds/thread per tile); counted
// vmcnt(12/6/0). __launch_bounds__(256,2) caps regs at 256 -> 2 waves/SIMD.
// SUMMODE=1: store column-sums of relu(C) per 128-row m-tile.
// Grid: (N/256, M/128).
// ---------------------------------------------------------------------------
template <typename TC, bool RELU, int SUMMODE>
__global__ __launch_bounds__(256, 2) void mfma_gemm_pipe(
    const bf16_t* __restrict__ A1, const bf16_t* __restrict__ A2, int K1,
    const bf16_t* __restrict__ Wt, TC* __restrict__ C,
    int M, int N, int K)
{
    __shared__ bf16_t As[3][4096];   // 3 x [128][32] = 24KB
    __shared__ bf16_t Bs[3][8192];   // 3 x [256][32] = 48KB

    const int tid = threadIdx.x;
    const int nwg = gridDim.x * gridDim.y;
    const int swz = xcd_swizzle(blockIdx.y * gridDim.x + blockIdx.x, nwg);
    const int mtile = swz / gridDim.x;
    const int ntile = swz - mtile * gridDim.x;
    const int m0 = mtile * 128;
    const int n0 = ntile * 256;

    const int l = tid & 63;
    const int w = tid >> 6;
    const int wr = w >> 1, wc = w & 1;   // wave tile: rows wr*64, cols wc*128
    const int lr = l & 15, lk = l >> 4;

    f32x4 acc[4][8];
#pragma unroll
    for (int m = 0; m < 4; ++m)
#pragma unroll
        for (int n = 0; n < 8; ++n) acc[m][n] = {0.f, 0.f, 0.f, 0.f};

    auto STG = [&](int s, int slot) {
        const int kt = s * 32;
        const bf16_t* ap; int lda, kk;
        if (kt < K1) { ap = A1; lda = K1; kk = kt; }
        else         { ap = A2; lda = K - K1; kk = kt - K1; }
        stage_bf16(ap + (size_t)m0 * lda + kk, lda, As[slot], tid);              // 2
        stage_bf16(Wt + (size_t)n0 * K + kt, K, Bs[slot], tid);                  // 2
        stage_bf16(Wt + (size_t)(n0 + 128) * K + kt, K, Bs[slot] + 4096, tid);   // 2
    };

    const int nt = K >> 5;
    STG(0, 0);
    STG(1, 1);

    int cslot = 0;
    for (int t = 0; t < nt; ++t) {
        if (t + 2 < nt) {
            int s2 = cslot + 2; if (s2 >= 3) s2 -= 3;
            STG(t + 2, s2);
            asm volatile("s_waitcnt vmcnt(12)" ::: "memory");  // tile t landed
        } else if (t + 1 < nt) {
            asm volatile("s_waitcnt vmcnt(6)" ::: "memory");
        } else {
            asm volatile("s_waitcnt vmcnt(0)" ::: "memory");
        }
        __builtin_amdgcn_s_barrier();          // all waves' tile-t loads in LDS
        __builtin_amdgcn_sched_barrier(0);     // no hoist of ds_reads above

        const bf16_t* as = As[cslot];
        const bf16_t* bs = Bs[cslot];
        bf16x8 af[4], bfr[8];
#pragma unroll
        for (int m = 0; m < 4; ++m)
            af[m] = *reinterpret_cast<const bf16x8*>(
                as + (wr * 64 + m * 16 + lr) * 32 + lk * 8);
#pragma unroll
        for (int n = 0; n < 8; ++n)
            bfr[n] = *reinterpret_cast<const bf16x8*>(
                bs + (wc * 128 + n * 16 + lr) * 32 + lk * 8);

        __builtin_amdgcn_s_setprio(1);
#pragma unroll
        for (int m = 0; m < 4; ++m)
#pragma unroll
            for (int n = 0; n < 8; ++n)
                acc[m][n] = __builtin_amdgcn_mfma_f32_16x16x32_bf16(
                    af[m], bfr[n], acc[m][n], 0, 0, 0);
        __builtin_amdgcn_s_setprio(0);

        __builtin_amdgcn_sched_barrier(0);     // no sink of reads below
        __builtin_amdgcn_s_barrier();          // reads done -> slot reusable
        cslot = (cslot == 2) ? 0 : cslot + 1;
    }

    if (SUMMODE) {
        __shared__ float red[8][256];
        const int slot = wr * 4 + lk;
#pragma unroll
        for (int n = 0; n < 8; ++n) {
            float cs = 0.f;
#pragma unroll
            for (int m = 0; m < 4; ++m)
#pragma unroll
                for (int r = 0; r < 4; ++r)
                    cs += fmaxf(acc[m][n][r], 0.f);
            red[slot][wc * 128 + n * 16 + lr] = cs;
        }
        __syncthreads();
        {
            float s = 0.f;
#pragma unroll
            for (int s3 = 0; s3 < 8; ++s3) s += red[s3][tid];
            const int batch = mtile & 511, half = mtile >> 9;
            ((float*)C)[(size_t)batch * 1024 + half * 512 + n0 + tid] = s;
        }
        return;
    }

    const int lk4 = lk * 4;
#pragma unroll
    for (int m = 0; m < 4; ++m) {
        const int grow = m0 + wr * 64 + m * 16 + lk4;
#pragma unroll
        for (int n = 0; n < 8; ++n) {
            const int gcol = n0 + wc * 128 + n * 16 + lr;
#pragma unroll
            for (int r = 0; r < 4; ++r) {
                float v = acc[m][n][r];
                if (RELU) v = fmaxf(v, 0.f);
                store_c(C + (size_t)(grow + r) * N + gcol, v);
            }
        }
    }
}

// X fp32 -> bf16 convert: xb[0..HOFFE) = premise, [HOFFE..) = hypothesis.
__global__ __launch_bounds__(256) void xcvt_kernel(
    const float* __restrict__ P, const float* __restrict__ H,
    bf16_t* __restrict__ X)
{
    const size_t NG = 8388608;   // groups of 8 elements (2*HOFFE/8)
    for (size_t g = (size_t)blockIdx.x * 256 + threadIdx.x; g < NG;
         g += (size_t)gridDim.x * 256) {
        size_t i = g * 8;
        const float* s = (i < HOFFE) ? (P + i) : (H + (i - HOFFE));
        float4 f0 = ld4(s), f1 = ld4(s + 4);
        uint4 u = { pk2(f0.x, f0.y), pk2(f0.z, f0.w),
                    pk2(f1.x, f1.y), pk2(f1.z, f1.w) };
        *reinterpret_cast<uint4*>(X + i) = u;
    }
}

// ---------------------------------------------------------------------------
// 2-phase 128x128 MFMA GEMM (scores + path-B fp32-A GEMMs).
// ---------------------------------------------------------------------------
template <typename TA1, typename TC, bool RELU, int SUMMODE>
__global__ __launch_bounds__(256) void mfma_gemm_kernel(
    const TA1* __restrict__ A1, const bf16_t* __restrict__ A2, int K1,
    const bf16_t* __restrict__ Wt, TC* __restrict__ C,
    int M, int N, int K,
    long long saA, long long saB, long long saC)
{
    __shared__ bf16_t As[4096];
    __shared__ bf16_t Bs[4096];
    __shared__ float red[8][128];

    const int tid = threadIdx.x;
    const int z = blockIdx.z;

    const int nwg = gridDim.x * gridDim.y;
    const int swz = xcd_swizzle(blockIdx.y * gridDim.x + blockIdx.x, nwg);
    const int mtile = swz / gridDim.x;
    const int ntile = swz - mtile * gridDim.x;
    const int m0 = mtile * 128;
    const int n0 = ntile * 128;

    const TA1* a1    = A1 + (size_t)z * saA;
    const bf16_t* wt = Wt + (size_t)z * saB;

    const int l = tid & 63;
    const int w = tid >> 6;
    const int wr = w >> 1, wc = w & 1;
    const int lr = l & 15, lk = l >> 4;

    f32x4 acc[4][4];
#pragma unroll
    for (int m = 0; m < 4; ++m)
#pragma unroll
        for (int n = 0; n < 4; ++n) acc[m][n] = {0.f, 0.f, 0.f, 0.f};

    for (int kt = 0; kt < K; kt += 32) {
        if (kt < K1)
            stage_any(a1 + (size_t)m0 * K1 + kt, K1, As, tid);
        else
            stage_bf16(A2 + (size_t)m0 * (K - K1) + (kt - K1), K - K1, As, tid);
        stage_bf16(wt + (size_t)n0 * K + kt, K, Bs, tid);
        __syncthreads();

        bf16x8 af[4], bfr[4];
#pragma unroll
        for (int m = 0; m < 4; ++m)
            af[m] = *reinterpret_cast<const bf16x8*>(
                As + (wr * 64 + m * 16 + lr) * 32 + lk * 8);
#pragma unroll
        for (int n = 0; n < 4; ++n)
            bfr[n] = *reinterpret_cast<const bf16x8*>(
                Bs + (wc * 64 + n * 16 + lr) * 32 + lk * 8);
#pragma unroll
        for (int m = 0; m < 4; ++m)
#pragma unroll
            for (int n = 0; n < 4; ++n)
                acc[m][n] = __builtin_amdgcn_mfma_f32_16x16x32_bf16(
                    af[m], bfr[n], acc[m][n], 0, 0, 0);
        __syncthreads();
    }

    if (SUMMODE) {
        const int slot = wr * 4 + lk;
#pragma unroll
        for (int n = 0; n < 4; ++n) {
            float cs = 0.f;
#pragma unroll
            for (int m = 0; m < 4; ++m)
#pragma unroll
                for (int r = 0; r < 4; ++r)
                    cs += fmaxf(acc[m][n][r], 0.f);
            red[slot][wc * 64 + n * 16 + lr] = cs;
        }
        __syncthreads();
        if (tid < 128) {
            float s = 0.f;
#pragma unroll
            for (int s3 = 0; s3 < 8; ++s3) s += red[s3][tid];
            const int batch = mtile & 511, half = mtile >> 9;
            ((float*)C)[(size_t)batch * 1024 + half * 512 + n0 + tid] = s;
        }
        return;
    }

    TC* cp = C + (size_t)z * saC;
    const int lk4 = lk * 4;
#pragma unroll
    for (int m = 0; m < 4; ++m) {
        const int grow = m0 + wr * 64 + m * 16 + lk4;
#pragma unroll
        for (int n = 0; n < 4; ++n) {
            const int gcol = n0 + wc * 64 + n * 16 + lr;
#pragma unroll
            for (int r = 0; r < 4; ++r) {
                float v = acc[m][n][r];
                if (RELU) v = fmaxf(v, 0.f);
                store_c(cp + (size_t)(grow + r) * N + gcol, v);
            }
        }
    }
}

// ---------------------------------------------------------------------------
// Small-matrix MFMA GEMM: 64x64 tile (aggregate FFN).
// ---------------------------------------------------------------------------
template <bool RELU>
__global__ __launch_bounds__(256) void mfma_gemm_small(
    const float* __restrict__ A, const bf16_t* __restrict__ Wt,
    float* __restrict__ C, int M, int N, int K)
{
    __shared__ bf16_t As[2048];
    __shared__ bf16_t Bs[2048];

    const int tid = threadIdx.x;
    const int nwg = gridDim.x * gridDim.y;
    const int swz = xcd_swizzle(blockIdx.y * gridDim.x + blockIdx.x, nwg);
    const int mtile = swz / gridDim.x;
    const int ntile = swz - mtile * gridDim.x;
    const int m0 = mtile * 64;
    const int n0 = ntile * 64;

    const int l = tid & 63, w = tid >> 6;
    const int wr = w >> 1, wc = w & 1;
    const int lr = l & 15, lk = l >> 4;

    f32x4 acc[2][2];
#pragma unroll
    for (int m = 0; m < 2; ++m)
#pragma unroll
        for (int n = 0; n < 2; ++n) acc[m][n] = {0.f, 0.f, 0.f, 0.f};

    const int arow = tid >> 2;
    const int aseg = (tid & 3) * 8;

    for (int kt = 0; kt < K; kt += 32) {
        const float* s = A + (size_t)(m0 + arow) * K + kt + aseg;
        float4 f0 = ld4(s), f1 = ld4(s + 4);
        uint4 u = { pk2(f0.x, f0.y), pk2(f0.z, f0.w),
                    pk2(f1.x, f1.y), pk2(f1.z, f1.w) };
        __syncthreads();
        *reinterpret_cast<uint4*>(As + arow * 32 + aseg) = u;
        {
            const int row = w * 16 + (l >> 2);
            const int ce  = (l & 3) * 8;
            gload_lds16(Wt + (size_t)(n0 + row) * K + kt + ce, Bs + w * 512);
        }
        __syncthreads();

        bf16x8 af[2], bfr[2];
#pragma unroll
        for (int m = 0; m < 2; ++m)
            af[m] = *reinterpret_cast<const bf16x8*>(
                As + (wr * 32 + m * 16 + lr) * 32 + lk * 8);
#pragma unroll
        for (int n = 0; n < 2; ++n)
            bfr[n] = *reinterpret_cast<const bf16x8*>(
                Bs + (wc * 32 + n * 16 + lr) * 32 + lk * 8);
#pragma unroll
        for (int m = 0; m < 2; ++m)
#pragma unroll
            for (int n = 0; n < 2; ++n)
                acc[m][n] = __builtin_amdgcn_mfma_f32_16x16x32_bf16(
                    af[m], bfr[n], acc[m][n], 0, 0, 0);
    }

    const int lk4 = lk * 4;
#pragma unroll
    for (int m = 0; m < 2; ++m) {
        const int grow = m0 + wr * 32 + m * 16 + lk4;
#pragma unroll
        for (int n = 0; n < 2; ++n) {
            const int gcol = n0 + wc * 32 + n * 16 + lr;
#pragma unroll
            for (int r = 0; r < 4; ++r) {
                float v = acc[m][n][r];
                if (RELU) v = fmaxf(v, 0.f);
                C[(size_t)(grow + r) * N + gcol] = v;
            }
        }
    }
}

// ---------------------------------------------------------------------------
// Fused softmax + alignment via MFMA. grid (512 batches, 2 modes).
// TS = source element type (bf16 xb on path A, fp32 raw inputs on path B).
// ---------------------------------------------------------------------------
__device__ inline unsigned pkpair(const float* s, int k, int col) {
    return pk2(s[(size_t)k * 512 + col], s[(size_t)(k + 1) * 512 + col]);
}
__device__ inline unsigned pkpair(const bf16_t* s, int k, int col) {
    return ((unsigned)s[(size_t)(k + 1) * 512 + col] << 16)
         | (unsigned)s[(size_t)k * 512 + col];
}

template <typename TS>
__global__ __launch_bounds__(256) void align_mfma_kernel(
    const float* __restrict__ S, const TS* __restrict__ prem,
    const TS* __restrict__ hyp, bf16_t* __restrict__ Out)
{
    const int b = blockIdx.x;
    const int mode = blockIdx.y;
    __shared__ bf16_t E[128][136];
    __shared__ bf16_t Bs[128][36];

    const int tid = threadIdx.x;
    const float* sp  = S + (size_t)b * 16384;
    const TS* src = (mode == 0 ? hyp : prem) + (size_t)b * 65536;
    bf16_t* outp = Out + (size_t)mode * HOFFE + (size_t)b * 65536;

    if (mode == 0) {
        const int r = tid >> 1, seg = (tid & 1) * 64;
#pragma unroll
        for (int i = 0; i < 16; ++i) {
            float4 v = ld4(sp + (size_t)r * 128 + seg + i * 4);
            uint2 u = { pk2(v.x, v.y), pk2(v.z, v.w) };
            *reinterpret_cast<uint2*>(&E[r][seg + i * 4]) = u;
        }
    } else {
#pragma unroll
        for (int it = 0; it < 16; ++it) {
            int i = tid + it * 256;
            int c = i >> 5, r4 = (i & 31) << 2;
            float4 v = ld4(sp + (size_t)c * 128 + r4);
            E[r4 + 0][c] = f2bf(v.x); E[r4 + 1][c] = f2bf(v.y);
            E[r4 + 2][c] = f2bf(v.z); E[r4 + 3][c] = f2bf(v.w);
        }
    }
    __syncthreads();

    {
        const int r = tid >> 1, seg = (tid & 1) * 64;
        float m = -1e30f;
#pragma unroll
        for (int i = 0; i < 32; ++i) {
            unsigned u = *reinterpret_cast<const unsigned*>(&E[r][seg + i * 2]);
            m = fmaxf(m, fmaxf(bf2f((bf16_t)(u & 0xffff)), bf2f((bf16_t)(u >> 16))));
        }
        m = fmaxf(m, __shfl_xor(m, 1));
        float s = 0.f;
#pragma unroll
        for (int i = 0; i < 32; ++i) {
            unsigned u = *reinterpret_cast<const unsigned*>(&E[r][seg + i * 2]);
            s += __expf(bf2f((bf16_t)(u & 0xffff)) - m)
               + __expf(bf2f((bf16_t)(u >> 16)) - m);
        }
        s += __shfl_xor(s, 1);
        const float inv = 1.f / s;
#pragma unroll
        for (int i = 0; i < 32; ++i) {
            unsigned u = *reinterpret_cast<const unsigned*>(&E[r][seg + i * 2]);
            float p0 = __expf(bf2f((bf16_t)(u & 0xffff)) - m) * inv;
            float p1 = __expf(bf2f((bf16_t)(u >> 16)) - m) * inv;
            *reinterpret_cast<unsigned*>(&E[r][seg + i * 2]) = pk2(p0, p1);
        }
    }

    const int l = tid & 63, w = tid >> 6;
    const int wr = w >> 1, wc = w & 1;
    const int lr = l & 15, lk = l >> 4;
    const int sn  = tid & 127;
    const int skh = tid >> 7;

    for (int nt = 0; nt < 4; ++nt) {
        const int n0 = nt * 128;
        f32x4 acc[4][4];
#pragma unroll
        for (int m = 0; m < 4; ++m)
#pragma unroll
            for (int n = 0; n < 4; ++n) acc[m][n] = {0.f, 0.f, 0.f, 0.f};

        for (int kt = 0; kt < 4; ++kt) {
            const int k0 = kt * 32;
            unsigned pkv[8];
#pragma unroll
            for (int j = 0; j < 8; ++j) {
                const int k = k0 + (skh * 8 + j) * 2;
                pkv[j] = pkpair(src, k, n0 + sn);
            }
            __syncthreads();
#pragma unroll
            for (int j = 0; j < 8; ++j)
                *reinterpret_cast<unsigned*>(&Bs[sn][(skh * 8 + j) * 2]) = pkv[j];
            __syncthreads();

            bf16x8 af[4], bfr[4];
#pragma unroll
            for (int m = 0; m < 4; ++m)
                af[m] = *reinterpret_cast<const bf16x8*>(
                    &E[wr * 64 + m * 16 + lr][k0 + lk * 8]);
#pragma unroll
            for (int n = 0; n < 4; ++n) {
                const bf16_t* bp = &Bs[wc * 64 + n * 16 + lr][lk * 8];
                union { bf16x8 v; uint2 u[2]; } t2;
                t2.u[0] = *reinterpret_cast<const uint2*>(bp);
                t2.u[1] = *reinterpret_cast<const uint2*>(bp + 4);
                bfr[n] = t2.v;
            }
#pragma unroll
            for (int m = 0; m < 4; ++m)
#pragma unroll
                for (int n = 0; n < 4; ++n)
                    acc[m][n] = __builtin_amdgcn_mfma_f32_16x16x32_bf16(
                        af[m], bfr[n], acc[m][n], 0, 0, 0);
        }

        const int lk4 = lk * 4;
#pragma unroll
        for (int m = 0; m < 4; ++m) {
            const int grow = wr * 64 + m * 16 + lk4;
#pragma unroll
            for (int n = 0; n < 4; ++n) {
                const int gcol = n0 + wc * 64 + n * 16 + lr;
#pragma unroll
                for (int r = 0; r < 4; ++r)
                    outp[(size_t)(grow + r) * 512 + gcol] = f2bf(acc[m][n][r]);
            }
        }
        __syncthreads();
    }
}

// Weight convert+transpose: W fp32 [K,N] -> Wt bf16 [N,K]. Grid (K/32, N/32).
__global__ __launch_bounds__(256) void wcvt_transpose(
    const float* __restrict__ W, bf16_t* __restrict__ Wt, int K, int N)
{
    __shared__ float t[32][33];
    const int k0 = blockIdx.x * 32, n0 = blockIdx.y * 32;
    const int r = threadIdx.x >> 3;
    const int c = (threadIdx.x & 7) * 4;
    float4 v = ld4(W + (size_t)(k0 + r) * N + n0 + c);
    t[r][c] = v.x; t[r][c + 1] = v.y; t[r][c + 2] = v.z; t[r][c + 3] = v.w;
    __syncthreads();
    ushort4 o;
    o.x = f2bf(t[c + 0][r]); o.y = f2bf(t[c + 1][r]);
    o.z = f2bf(t[c + 2][r]); o.w = f2bf(t[c + 3][r]);
    *reinterpret_cast<ushort4*>(Wt + (size_t)(n0 + r) * K + k0 + c) = o;
}

// ===========================================================================
// Round-2 kernels (VALU path; fallback only)
// ===========================================================================

template <typename TA1, typename TA2, typename TC>
__global__ __launch_bounds__(256) void gemm_relu_kernel(
    const TA1* __restrict__ A1, const TA2* __restrict__ A2, int K1,
    const float* __restrict__ W, TC* __restrict__ C,
    int M, int N, int K)
{
    __shared__ __align__(16) float As[8][132];
    __shared__ __align__(16) float Bs[8][132];

    const int tid = threadIdx.x;
    const int tx = tid & 15;
    const int ty = tid >> 4;
    const int m0 = blockIdx.y * 128;
    const int n0 = blockIdx.x * 128;

    const int arow = tid >> 1;
    const int apart = tid & 1;
    const int brow = tid >> 5;
    const int bcol = (tid & 31) << 2;

    float acc[8][8];
#pragma unroll
    for (int i = 0; i < 8; ++i)
#pragma unroll
        for (int j = 0; j < 8; ++j) acc[i][j] = 0.f;

    for (int kt = 0; kt < K; kt += 8) {
        float4 av;
        if (kt < K1)
            av = ld4(A1 + (size_t)(m0 + arow) * K1 + kt + apart * 4);
        else
            av = ld4(A2 + (size_t)(m0 + arow) * (K - K1) + (kt - K1) + apart * 4);
        float4 bv = ld4(W + (size_t)(kt + brow) * N + n0 + bcol);

        __syncthreads();
        As[apart * 4 + 0][arow] = av.x;
        As[apart * 4 + 1][arow] = av.y;
        As[apart * 4 + 2][arow] = av.z;
        As[apart * 4 + 3][arow] = av.w;
        *reinterpret_cast<float4*>(&Bs[brow][bcol]) = bv;
        __syncthreads();

#pragma unroll
        for (int k = 0; k < 8; ++k) {
            float4 a0 = *reinterpret_cast<const float4*>(&As[k][ty * 8]);
            float4 a1 = *reinterpret_cast<const float4*>(&As[k][ty * 8 + 4]);
            float4 b0 = *reinterpret_cast<const float4*>(&Bs[k][tx * 8]);
            float4 b1 = *reinterpret_cast<const float4*>(&Bs[k][tx * 8 + 4]);
            float a[8] = {a0.x, a0.y, a0.z, a0.w, a1.x, a1.y, a1.z, a1.w};
            float b[8] = {b0.x, b0.y, b0.z, b0.w, b1.x, b1.y, b1.z, b1.w};
#pragma unroll
            for (int i = 0; i < 8; ++i)
#pragma unroll
                for (int j = 0; j < 8; ++j)
                    acc[i][j] = fmaf(a[i], b[j], acc[i][j]);
        }
    }

#pragma unroll
    for (int i = 0; i < 8; ++i) {
        float4 v0, v1;
        v0.x = fmaxf(acc[i][0], 0.f); v0.y = fmaxf(acc[i][1], 0.f);
        v0.z = fmaxf(acc[i][2], 0.f); v0.w = fmaxf(acc[i][3], 0.f);
        v1.x = fmaxf(acc[i][4], 0.f); v1.y = fmaxf(acc[i][5], 0.f);
        v1.z = fmaxf(acc[i][6], 0.f); v1.w = fmaxf(acc[i][7], 0.f);
        size_t off = (size_t)(m0 + ty * 8 + i) * N + n0 + tx * 8;
        st4(C + off, v0);
        st4(C + off + 4, v1);
    }
}

__global__ __launch_bounds__(256) void scores_valu_kernel(
    const bf16_t* __restrict__ Pp, const bf16_t* __restrict__ Ph,
    float* __restrict__ S)
{
    const int b = blockIdx.x;
    __shared__ __align__(16) float Ap[16][132];
    __shared__ __align__(16) float Bh[16][132];

    const int tid = threadIdx.x;
    const int tx = tid & 15, ty = tid >> 4;
    const bf16_t* pa = Pp + (size_t)b * 65536;
    const bf16_t* pb = Ph + (size_t)b * 65536;
    const int lrow = tid >> 2;
    const int lq = tid & 3;

    float acc[8][8];
#pragma unroll
    for (int i = 0; i < 8; ++i)
#pragma unroll
        for (int j = 0; j < 8; ++j) acc[i][j] = 0.f;

    for (int kt = 0; kt < 512; kt += 16) {
        __syncthreads();
#pragma unroll
        for (int h = 0; h < 2; ++h) {
            int row = lrow + h * 64;
            float4 v = ld4(pa + (size_t)row * 512 + kt + lq * 4);
            Ap[lq * 4 + 0][row] = v.x; Ap[lq * 4 + 1][row] = v.y;
            Ap[lq * 4 + 2][row] = v.z; Ap[lq * 4 + 3][row] = v.w;
            float4 w2 = ld4(pb + (size_t)row * 512 + kt + lq * 4);
            Bh[lq * 4 + 0][row] = w2.x; Bh[lq * 4 + 1][row] = w2.y;
            Bh[lq * 4 + 2][row] = w2.z; Bh[lq * 4 + 3][row] = w2.w;
        }
        __syncthreads();
#pragma unroll
        for (int k = 0; k < 16; ++k) {
            float4 a0 = *reinterpret_cast<const float4*>(&Ap[k][ty * 8]);
            float4 a1 = *reinterpret_cast<const float4*>(&Ap[k][ty * 8 + 4]);
            float4 b0 = *reinterpret_cast<const float4*>(&Bh[k][tx * 8]);
            float4 b1 = *reinterpret_cast<const float4*>(&Bh[k][tx * 8 + 4]);
            float a[8] = {a0.x, a0.y, a0.z, a0.w, a1.x, a1.y, a1.z, a1.w};
            float b[8] = {b0.x, b0.y, b0.z, b0.w, b1.x, b1.y, b1.z, b1.w};
#pragma unroll
            for (int i = 0; i < 8; ++i)
#pragma unroll
                for (int j = 0; j < 8; ++j)
                    acc[i][j] = fmaf(a[i], b[j], acc[i][j]);
        }
    }

    float* sp = S + (size_t)b * 16384;
#pragma unroll
    for (int i = 0; i < 8; ++i) {
        float4 v0 = {acc[i][0], acc[i][1], acc[i][2], acc[i][3]};
        float4 v1 = {acc[i][4], acc[i][5], acc[i][6], acc[i][7]};
        size_t off = (size_t)(ty * 8 + i) * 128 + tx * 8;
        *reinterpret_cast<float4*>(sp + off)     = v0;
        *reinterpret_cast<float4*>(sp + off + 4) = v1;
    }
}

template <int MODE>
__global__ __launch_bounds__(256) void align_kernel(
    const float* __restrict__ S, const float* __restrict__ Src,
    bf16_t* __restrict__ Out)
{
    const int b = blockIdx.x;
    __shared__ __align__(16) float E[64][132];
    __shared__ __align__(16) float Hs[16][132];
    __shared__ float statm[64], stati[64];

    const int tid = threadIdx.x;
    const int ty = tid >> 5;
    const int tx = tid & 31;
    const float* sp = S + (size_t)b * 16384;
    const float* src = Src + (size_t)b * 65536;
    bf16_t* outp = Out + (size_t)b * 65536;

    for (int h0 = 0; h0 < 128; h0 += 64) {
        __syncthreads();
        if (MODE == 0) {
            for (int idx = tid; idx < 2048; idx += 256) {
                int r = idx >> 5, c4 = (idx & 31) << 2;
                float4 v = ld4(sp + (size_t)(h0 + r) * 128 + c4);
                E[r][c4 + 0] = v.x; E[r][c4 + 1] = v.y;
                E[r][c4 + 2] = v.z; E[r][c4 + 3] = v.w;
            }
        } else {
            for (int idx = tid; idx < 2048; idx += 256) {
                int c = idx >> 4, r4 = (idx & 15) << 2;
                float4 v = ld4(sp + (size_t)c * 128 + h0 + r4);
                E[r4 + 0][c] = v.x; E[r4 + 1][c] = v.y;
                E[r4 + 2][c] = v.z; E[r4 + 3][c] = v.w;
            }
        }
        __syncthreads();

        if (tid < 64) {
            float m = -1e30f;
            for (int c = 0; c < 128; ++c) m = fmaxf(m, E[tid][c]);
            float s = 0.f;
            for (int c = 0; c < 128; ++c) s += __expf(E[tid][c] - m);
            statm[tid] = m;
            stati[tid] = 1.f / s;
        }
        __syncthreads();

        for (int idx = tid; idx < 8192; idx += 256) {
            int r = idx >> 7, c = idx & 127;
            E[r][c] = __expf(E[r][c] - statm[r]) * stati[r];
        }

        for (int dc = 0; dc < 4; ++dc) {
            float acc[8][4];
#pragma unroll
            for (int i = 0; i < 8; ++i)
#pragma unroll
                for (int j = 0; j < 4; ++j) acc[i][j] = 0.f;

            for (int ct = 0; ct < 8; ++ct) {
                __syncthreads();
                for (int idx = tid; idx < 512; idx += 256) {
                    int r = idx >> 5, c4 = (idx & 31) << 2;
                    float4 v = ld4(src + (size_t)(ct * 16 + r) * 512 + dc * 128 + c4);
                    *reinterpret_cast<float4*>(&Hs[r][c4]) = v;
                }
                __syncthreads();
#pragma unroll
                for (int k = 0; k < 16; ++k) {
                    int c = ct * 16 + k;
                    float a[8];
#pragma unroll
                    for (int i = 0; i < 8; ++i) a[i] = E[ty * 8 + i][c];
                    float4 b4 = *reinterpret_cast<const float4*>(&Hs[k][tx * 4]);
                    float bb[4] = {b4.x, b4.y, b4.z, b4.w};
#pragma unroll
                    for (int i = 0; i < 8; ++i)
#pragma unroll
                        for (int j = 0; j < 4; ++j)
                            acc[i][j] = fmaf(a[i], bb[j], acc[i][j]);
                }
            }
#pragma unroll
            for (int i = 0; i < 8; ++i) {
                float4 v = {acc[i][0], acc[i][1], acc[i][2], acc[i][3]};
                st4(outp + (size_t)(h0 + ty * 8 + i) * 512 + dc * 128 + tx * 4, v);
            }
        }
    }
}

__global__ __launch_bounds__(128) void seqsum_kernel(
    const bf16_t* __restrict__ Cmp, float* __restrict__ Agg)
{
    const int b = blockIdx.x;
    const int half = blockIdx.y;
    const bf16_t* base = Cmp + (size_t)half * HOFFE + (size_t)b * 65536 + threadIdx.x * 4;
    float4 s = {0.f, 0.f, 0.f, 0.f};
    for (int r = 0; r < 128; ++r) {
        ushort4 u = *reinterpret_cast<const ushort4*>(base + (size_t)r * 512);
        s.x += bf2f(u.x); s.y += bf2f(u.y); s.z += bf2f(u.z); s.w += bf2f(u.w);
    }
    *reinterpret_cast<float4*>(Agg + (size_t)b * 1024 + half * 512 + threadIdx.x * 4) = s;
}

__global__ __launch_bounds__(64) void scorer_kernel(
    const float* __restrict__ H, const float* __restrict__ Wsc,
    float* __restrict__ Out)
{
    const int row = blockIdx.x;
    const int l = threadIdx.x;
    float a0 = 0.f, a1 = 0.f;
    for (int h = l; h < 512; h += 64) {
        float v = H[(size_t)row * 512 + h];
        a0 = fmaf(v, Wsc[h * 2 + 0], a0);
        a1 = fmaf(v, Wsc[h * 2 + 1], a1);
    }
#pragma unroll
    for (int off = 32; off > 0; off >>= 1) {
        a0 += __shfl_down(a0, off);
        a1 += __shfl_down(a1, off);
    }
    if (l == 0) {
        float m = fmaxf(a0, a1);
        float e0 = __expf(a0 - m), e1 = __expf(a1 - m);
        float inv = 1.f / (e0 + e1);
        Out[row * 2 + 0] = e0 * inv;
        Out[row * 2 + 1] = e1 * inv;
    }
}

// ===========================================================================
extern "C" void kernel_launch(void* const* d_in, const int* in_sizes, int n_in,
                              void* d_out, int out_size, void* d_ws, size_t ws_size,
                              hipStream_t stream)
{
    const float* premise    = (const float*)d_in[0];
    const float* hypothesis = (const float*)d_in[1];
    const float* aw0 = (const float*)d_in[2];
    const float* aw1 = (const float*)d_in[3];
    const float* cw0 = (const float*)d_in[4];
    const float* cw1 = (const float*)d_in[5];
    const float* gw0 = (const float*)d_in[6];
    const float* gw1 = (const float*)d_in[7];
    const float* wsc = (const float*)d_in[8];
    float* out = (float*)d_out;

    char* ws = (char*)d_ws;
    dim3 blk(256);

    const size_t MB128 = 134217728ull;
    const size_t NEED_A = 3 * MB128 + 4194304 + 4194304;
    const size_t NEED_B = 2 * MB128 + 4194304 + 4194304;

    if (ws_size >= NEED_A) {
        // ---------------- path A: full pipeline, all-bf16 big GEMMs --------
        bf16_t* xb = (bf16_t*)ws;                       // [131072,512] bf16
        bf16_t* r0 = (bf16_t*)(ws + MB128);             // T1 -> (scores) -> C1
        bf16_t* r1 = (bf16_t*)(ws + 2 * MB128);         // proj -> align
        float* scoresF = (float*)(ws + MB128);          // overlays r0 (T1 dead)
        const size_t WOFF = 3 * MB128;
        bf16_t* awt0 = (bf16_t*)(ws + WOFF);
        bf16_t* awt1 = awt0 + 262144;
        bf16_t* cwt0 = awt1 + 262144;
        bf16_t* cwt1 = cwt0 + 524288;
        bf16_t* gwt0 = cwt1 + 262144;
        bf16_t* gwt1 = gwt0 + 524288;
        float* aggF  = (float*)(ws + WOFF + 4194304);
        float* hid1F = aggF + 524288;
        float* hid2F = hid1F + 262144;

        xcvt_kernel<<<2048, blk, 0, stream>>>(premise, hypothesis, xb);
        wcvt_transpose<<<dim3(16, 16), blk, 0, stream>>>(aw0, awt0, 512, 512);
        wcvt_transpose<<<dim3(16, 16), blk, 0, stream>>>(aw1, awt1, 512, 512);
        wcvt_transpose<<<dim3(32, 16), blk, 0, stream>>>(cw0, cwt0, 1024, 512);
        wcvt_transpose<<<dim3(16, 16), blk, 0, stream>>>(cw1, cwt1, 512, 512);
        wcvt_transpose<<<dim3(32, 16), blk, 0, stream>>>(gw0, gwt0, 1024, 512);
        wcvt_transpose<<<dim3(16, 16), blk, 0, stream>>>(gw1, gwt1, 512, 512);

        // 1. Attend L1 (both sentences): T1 = relu(xb @ aw0) -> r0
        mfma_gemm_pipe<bf16_t, true, 0><<<dim3(2, 1024), blk, 0, stream>>>(
            xb, xb, 512, awt0, r0, 131072, 512, 512);
        // 2. Attend L2: proj = relu(T1 @ aw1) -> r1
        mfma_gemm_pipe<bf16_t, true, 0><<<dim3(2, 1024), blk, 0, stream>>>(
            r0, r0, 512, awt1, r1, 131072, 512, 512);
        // 3. scores[b] = proj_p[b] @ proj_h[b]^T -> scoresF (overlays r0)
        mfma_gemm_kernel<bf16_t, float, false, 0><<<dim3(1, 1, 512), blk, 0, stream>>>(
            r1, nullptr, 512, r1 + HOFFE, scoresF, 128, 128, 512,
            65536LL, 65536LL, 16384LL);
        // 4. alignments -> r1 (overwrites proj); src = bf16 xb
        align_mfma_kernel<bf16_t><<<dim3(512, 2), blk, 0, stream>>>(
            scoresF, xb, xb + HOFFE, r1);
        // 5. Compare L1: relu([xb | align] @ cw0) -> r0
        mfma_gemm_pipe<bf16_t, true, 0><<<dim3(2, 1024), blk, 0, stream>>>(
            xb, r1, 512, cwt0, r0, 131072, 512, 1024);
        // 6. Compare L2 fused seq-sum -> aggregated
        mfma_gemm_pipe<float, true, 1><<<dim3(2, 1024), blk, 0, stream>>>(
            r0, r0, 512, cwt1, aggF, 131072, 512, 512);
        // 7. Aggregate FFN + scorer
        mfma_gemm_small<true><<<dim3(8, 8), blk, 0, stream>>>(
            aggF, gwt0, hid1F, 512, 512, 1024);
        mfma_gemm_small<true><<<dim3(8, 8), blk, 0, stream>>>(
            hid1F, gwt1, hid2F, 512, 512, 512);
        scorer_kernel<<<512, 64, 0, stream>>>(hid2F, wsc, out);
    } else if (ws_size >= NEED_B) {
        // ---------------- path B: round-6 layout; pipe for bf16-A GEMMs ----
        bf16_t* r0 = (bf16_t*)ws;
        bf16_t* r1 = (bf16_t*)(ws + MB128);
        float* scoresF = (float*)ws;
        const size_t WOFF = 2 * MB128;
        bf16_t* awt0 = (bf16_t*)(ws + WOFF);
        bf16_t* awt1 = awt0 + 262144;
        bf16_t* cwt0 = awt1 + 262144;
        bf16_t* cwt1 = cwt0 + 524288;
        bf16_t* gwt0 = cwt1 + 262144;
        bf16_t* gwt1 = gwt0 + 524288;
        float* aggF  = (float*)(ws + WOFF + 4194304);
        float* hid1F = aggF + 524288;
        float* hid2F = hid1F + 262144;

        wcvt_transpose<<<dim3(16, 16), blk, 0, stream>>>(aw0, awt0, 512, 512);
        wcvt_transpose<<<dim3(16, 16), blk, 0, stream>>>(aw1, awt1, 512, 512);
        wcvt_transpose<<<dim3(32, 16), blk, 0, stream>>>(cw0, cwt0, 1024, 512);
        wcvt_transpose<<<dim3(16, 16), blk, 0, stream>>>(cw1, cwt1, 512, 512);
        wcvt_transpose<<<dim3(32, 16), blk, 0, stream>>>(gw0, gwt0, 1024, 512);
        wcvt_transpose<<<dim3(16, 16), blk, 0, stream>>>(gw1, gwt1, 512, 512);

        mfma_gemm_kernel<float, bf16_t, true, 0><<<dim3(4, 512, 1), blk, 0, stream>>>(
            premise, nullptr, 512, awt0, r0, 65536, 512, 512, 0, 0, 0);
        mfma_gemm_kernel<float, bf16_t, true, 0><<<dim3(4, 512, 1), blk, 0, stream>>>(
            hypothesis, nullptr, 512, awt0, r0 + HOFFE, 65536, 512, 512, 0, 0, 0);
        mfma_gemm_pipe<bf16_t, true, 0><<<dim3(2, 1024), blk, 0, stream>>>(
            r0, r0, 512, awt1, r1, 131072, 512, 512);
        mfma_gemm_kernel<bf16_t, float, false, 0><<<dim3(1, 1, 512), blk, 0, stream>>>(
            r1, nullptr, 512, r1 + HOFFE, scoresF, 128, 128, 512,
            65536LL, 65536LL, 16384LL);
        align_mfma_kernel<float><<<dim3(512, 2), blk, 0, stream>>>(
            scoresF, premise, hypothesis, r1);
        mfma_gemm_kernel<float, bf16_t, true, 0><<<dim3(4, 512, 1), blk, 0, stream>>>(
            premise, r1, 512, cwt0, r0, 65536, 512, 1024, 0, 0, 0);
        mfma_gemm_kernel<float, bf16_t, true, 0><<<dim3(4, 512, 1), blk, 0, stream>>>(
            hypothesis, r1 + HOFFE, 512, cwt0, r0 + HOFFE, 65536, 512, 1024, 0, 0, 0);
        mfma_gemm_pipe<float, true, 1><<<dim3(2, 1024), blk, 0, stream>>>(
            r0, r0, 512, cwt1, aggF, 131072, 512, 512);
        mfma_gemm_small<true><<<dim3(8, 8), blk, 0, stream>>>(
            aggF, gwt0, hid1F, 512, 512, 1024);
        mfma_gemm_small<true><<<dim3(8, 8), blk, 0, stream>>>(
            hid1F, gwt1, hid2F, 512, 512, 512);
        scorer_kernel<<<512, 64, 0, stream>>>(hid2F, wsc, out);
    } else {
        // ---------------- path C: round-2 VALU fallback (complete) ---------
        bf16_t* r0 = (bf16_t*)ws;
        bf16_t* r1 = (bf16_t*)(ws + MB128);
        float* scoresF = (float*)ws;
        float* aggF  = (float*)ws;
        float* hid1F = (float*)(ws + (size_t)4194304);
        float* hid2F = (float*)(ws + (size_t)8388608);
        gemm_relu_kernel<float, bf16_t, bf16_t><<<dim3(4, 512), blk, 0, stream>>>(
            premise, nullptr, 512, aw0, r0, 65536, 512, 512);
        gemm_relu_kernel<float, bf16_t, bf16_t><<<dim3(4, 512), blk, 0, stream>>>(
            hypothesis, nullptr, 512, aw0, r0 + HOFFE, 65536, 512, 512);
        gemm_relu_kernel<bf16_t, bf16_t, bf16_t><<<dim3(4, 1024), blk, 0, stream>>>(
            r0, nullptr, 512, aw1, r1, 131072, 512, 512);
        scores_valu_kernel<<<512, blk, 0, stream>>>(r1, r1 + HOFFE, scoresF);
        align_kernel<0><<<512, blk, 0, stream>>>(scoresF, hypothesis, r1);
        align_kernel<1><<<512, blk, 0, stream>>>(scoresF, premise, r1 + HOFFE);
        gemm_relu_kernel<float, bf16_t, bf16_t><<<dim3(4, 512), blk, 0, stream>>>(
            premise, r1, 512, cw0, r0, 65536, 512, 1024);
        gemm_relu_kernel<float, bf16_t, bf16_t><<<dim3(4, 512), blk, 0, stream>>>(
            hypothesis, r1 + HOFFE, 512, cw0, r0 + HOFFE, 65536, 512, 1024);
        gemm_relu_kernel<bf16_t, bf16_t, bf16_t><<<dim3(4, 1024), blk, 0, stream>>>(
            r0, nullptr, 512, cw1, r1, 131072, 512, 512);
        seqsum_kernel<<<dim3(512, 2), 128, 0, stream>>>(r1, aggF);
        gemm_relu_kernel<float, bf16_t, float><<<dim3(4, 4), blk, 0, stream>>>(
            aggF, nullptr, 1024, gw0, hid1F, 512, 512, 1024);
        gemm_relu_kernel<float, bf16_t, float><<<dim3(4, 4), blk, 0, stream>>>(
            hid1F, nullptr, 512, gw1, hid2F, 512, 512, 512);
        scorer_kernel<<<512, 64, 0, stream>>>(hid2F, wsc, out);
    }
}

// Round 13
// 677.300 us; speedup vs baseline: 1.5669x; 1.1290x over previous
//
#include <hip/hip_runtime.h>
#include <cstddef>

// Decomposable Attention Entailment forward. B=512, P=Q=128, D=H=512.
// Round 13: fixed 8-phase 256x256 schedule. Round-12 raced: ds_reads for
// tile g were issued BEFORE the vmcnt confirming tile g's global_load_lds
// landed. Fix: confirmation (vmcnt + barrier) at END of the phase BEFORE
// the reads. Per phase: {ds_read confirmed | stage future} -> lgkm(0) ->
// MFMA -> [vmcnt(4) confirming next phase's data; vmcnt(0) at tail] ->
// barrier. Stage order A(k0),B(k0),A(k1),B(k1); 2 instr/half -> vmcnt(4)
// leaves the 2 newest halves in flight.

typedef unsigned short bf16_t;
typedef __attribute__((ext_vector_type(8))) short bf16x8;   // 8 bf16 = 4 VGPRs
typedef __attribute__((ext_vector_type(4))) float f32x4;

#define HOFFE ((size_t)33554432)   // elements per sentence tensor (512*128*512)

__device__ inline float bf2f(bf16_t u) {
    return __uint_as_float((unsigned)u << 16);
}
__device__ inline bf16_t f2bf(float f) {
    unsigned v = __float_as_uint(f);
    v += 0x7FFFu + ((v >> 16) & 1u);       // round-to-nearest-even
    return (bf16_t)(v >> 16);
}
__device__ inline unsigned pk2(float a, float b) {   // low = a, high = b
    return ((unsigned)f2bf(b) << 16) | (unsigned)f2bf(a);
}

__device__ inline float4 ld4(const float* p) {
    return *reinterpret_cast<const float4*>(p);
}
__device__ inline float4 ld4(const bf16_t* p) {
    ushort4 u = *reinterpret_cast<const ushort4*>(p);
    float4 f;
    f.x = bf2f(u.x); f.y = bf2f(u.y); f.z = bf2f(u.z); f.w = bf2f(u.w);
    return f;
}
__device__ inline void st4(float* p, float4 v) {
    *reinterpret_cast<float4*>(p) = v;
}
__device__ inline void st4(bf16_t* p, float4 v) {
    ushort4 u;
    u.x = f2bf(v.x); u.y = f2bf(v.y); u.z = f2bf(v.z); u.w = f2bf(v.w);
    *reinterpret_cast<ushort4*>(p) = u;
}

// Bijective XCD swizzle (learn_hip m204).
__device__ inline int xcd_swizzle(int orig, int nwg) {
    const int q = nwg >> 3, r = nwg & 7;
    const int xcd = orig & 7, idx = orig >> 3;
    return (xcd < r ? xcd * (q + 1) : r * (q + 1) + (xcd - r) * q) + idx;
}

// ===========================================================================
// MFMA GEMM machinery
// ===========================================================================

__device__ inline void gload_lds16(const bf16_t* g, bf16_t* l) {
    __builtin_amdgcn_global_load_lds(
        (const __attribute__((address_space(1))) unsigned int*)g,
        (__attribute__((address_space(3))) unsigned int*)l, 16, 0, 0);
}

// Stage a [128 x 32] bf16 tile into 8KB LDS (legacy, 256-thread kernels).
__device__ inline void stage_bf16(const bf16_t* __restrict__ src, int ld,
                                  bf16_t* dst, int tid) {
    const int l = tid & 63, w = tid >> 6;
#pragma unroll
    for (int i = 0; i < 2; ++i) {
        const int chunk = w * 2 + i;
        const int row = chunk * 16 + (l >> 2);
        const int ce  = (l & 3) * 8;
        gload_lds16(src + (size_t)row * ld + ce, dst + chunk * 512);
    }
}

__device__ inline void stage_f32(const float* __restrict__ src, int ld,
                                 bf16_t* dst, int tid) {
    const int row = tid >> 1;
    const int seg = (tid & 1) * 16;
    const float* s = src + (size_t)row * ld + seg;
    float4 f0 = ld4(s), f1 = ld4(s + 4), f2_ = ld4(s + 8), f3 = ld4(s + 12);
    uint4 u0 = { pk2(f0.x, f0.y), pk2(f0.z, f0.w), pk2(f1.x, f1.y), pk2(f1.z, f1.w) };
    uint4 u1 = { pk2(f2_.x, f2_.y), pk2(f2_.z, f2_.w), pk2(f3.x, f3.y), pk2(f3.z, f3.w) };
    *reinterpret_cast<uint4*>(dst + row * 32 + seg)     = u0;
    *reinterpret_cast<uint4*>(dst + row * 32 + seg + 8) = u1;
}

__device__ inline void stage_any(const bf16_t* src, int ld, bf16_t* dst, int tid) {
    stage_bf16(src, ld, dst, tid);
}
__device__ inline void stage_any(const float* src, int ld, bf16_t* dst, int tid) {
    stage_f32(src, ld, dst, tid);
}

__device__ inline void store_c(float* p, float v)  { *p = v; }
__device__ inline void store_c(bf16_t* p, float v) { *p = f2bf(v); }

// ---------------------------------------------------------------------------
// 8-phase 256x256 MFMA GEMM. 512 threads = 8 waves (2M x 4N), per-wave
// output 128x64 (acc[8][4]). BK=64 in two 32-col K-halves. LDS 128KB
// double-buffered; bank swizzle slot^=(row>>1)&3 on BOTH stage src + read.
// C = relu?([A1 | A2] @ Wt^T); SUMMODE=1: per-batch-half column sums.
// Grid (N/256, M/256).
// ---------------------------------------------------------------------------
template <typename TC, bool RELU, int SUMMODE>
__global__ __launch_bounds__(512, 2) void mfma_gemm_8ph(
    const bf16_t* __restrict__ A1, const bf16_t* __restrict__ A2, int K1,
    const bf16_t* __restrict__ Wt, TC* __restrict__ C,
    int M, int N, int K)
{
    __shared__ bf16_t lds[65536];   // 128KB

    const int tid = threadIdx.x;
    const int l = tid & 63, w = tid >> 6;
    const int wrM = w >> 2, wrN = w & 3;
    const int lr = l & 15, lk = l >> 4;

    const int nwg = gridDim.x * gridDim.y;
    const int swz = xcd_swizzle(blockIdx.y * gridDim.x + blockIdx.x, nwg);
    const int mtile = swz / gridDim.x;
    const int ntile = swz - mtile * gridDim.x;
    const int m0 = mtile * 256;
    const int n0 = ntile * 256;

    f32x4 acc[8][4];
#pragma unroll
    for (int i = 0; i < 8; ++i)
#pragma unroll
        for (int j = 0; j < 4; ++j) acc[i][j] = {0.f, 0.f, 0.f, 0.f};

    auto stage_half = [&](const bf16_t* gsrc, int ld, bf16_t* lbase) {
#pragma unroll
        for (int i = 0; i < 2; ++i) {
            const int si = i * 512 + w * 64 + l;
            const int row = si >> 2, slot = si & 3;
            const int cb = slot ^ ((row >> 1) & 3);
            gload_lds16(gsrc + (size_t)row * ld + cb * 8,
                        lds + 0 + (lbase - lds) + (size_t)(i * 512 + w * 64) * 8);
        }
    };
    auto stageA = [&](int buf, int kt, int kh) {
        const int kb = kt * 64 + kh * 32;
        const bf16_t* p; int ld;
        if (kb < K1) { p = A1 + (size_t)m0 * K1 + kb; ld = K1; }
        else         { p = A2 + (size_t)m0 * (K - K1) + (kb - K1); ld = K - K1; }
        stage_half(p, ld, lds + buf * 16384 + kh * 8192);
    };
    auto stageB = [&](int buf, int kt, int kh) {
        stage_half(Wt + (size_t)n0 * K + kt * 64 + kh * 32, K,
                   lds + 32768 + buf * 16384 + kh * 8192);
    };

    auto rdA4 = [&](bf16x8* af, int buf, int kh, int mh) {
        const bf16_t* base = lds + buf * 16384 + kh * 8192;
#pragma unroll
        for (int i = 0; i < 4; ++i) {
            const int R = wrM * 128 + (mh * 4 + i) * 16 + lr;
            const int sw = lk ^ ((R >> 1) & 3);
            af[i] = *reinterpret_cast<const bf16x8*>(base + R * 32 + sw * 8);
        }
    };
    auto rdB4 = [&](bf16x8* bq, int buf, int kh) {
        const bf16_t* base = lds + 32768 + buf * 16384 + kh * 8192;
#pragma unroll
        for (int i = 0; i < 4; ++i) {
            const int R = wrN * 64 + i * 16 + lr;
            const int sw = lk ^ ((R >> 1) & 3);
            bq[i] = *reinterpret_cast<const bf16x8*>(base + R * 32 + sw * 8);
        }
    };
    auto mfma16 = [&](bf16x8* af, bf16x8* bq, int mh) {
        __builtin_amdgcn_s_setprio(1);
#pragma unroll
        for (int i = 0; i < 4; ++i)
#pragma unroll
            for (int j = 0; j < 4; ++j)
                acc[mh * 4 + i][j] = __builtin_amdgcn_mfma_f32_16x16x32_bf16(
                    af[i], bq[j], acc[mh * 4 + i][j], 0, 0, 0);
        __builtin_amdgcn_s_setprio(0);
    };

    // ---- prologue: stage all of K-tile 0 (A k0, B k0, A k1, B k1), then
    // confirm the k0 halves landed (vmcnt(4): 2 newest halves may fly).
    stageA(0, 0, 0); stageB(0, 0, 0); stageA(0, 0, 1); stageB(0, 0, 1);
    asm volatile("s_waitcnt vmcnt(4)" ::: "memory");
    __builtin_amdgcn_s_barrier();
    __builtin_amdgcn_sched_barrier(0);

    const int nkt = K >> 6;
    bf16x8 af[4], bq[4];

    for (int g = 0; g < nkt; ++g) {
        const int cur = g & 1, nxt = cur ^ 1;
        const bool more = (g + 1 < nkt);

        // phase 0: (k0, mh0); prefetch A(g+1, k0)
        rdA4(af, cur, 0, 0); rdB4(bq, cur, 0);
        if (more) stageA(nxt, g + 1, 0);
        asm volatile("s_waitcnt lgkmcnt(0)" ::: "memory");
        __builtin_amdgcn_sched_barrier(0);
        mfma16(af, bq, 0);
        __builtin_amdgcn_sched_barrier(0);
        __builtin_amdgcn_s_barrier();
        __builtin_amdgcn_sched_barrier(0);

        // phase 1: (k0, mh1); prefetch B(g+1, k0); confirm (g, k1)
        rdA4(af, cur, 0, 1);
        if (more) stageB(nxt, g + 1, 0);
        asm volatile("s_waitcnt lgkmcnt(0)" ::: "memory");
        __builtin_amdgcn_sched_barrier(0);
        mfma16(af, bq, 1);
        __builtin_amdgcn_sched_barrier(0);
        if (more) asm volatile("s_waitcnt vmcnt(4)" ::: "memory");
        else      asm volatile("s_waitcnt vmcnt(0)" ::: "memory");
        __builtin_amdgcn_s_barrier();
        __builtin_amdgcn_sched_barrier(0);

        // phase 2: (k1, mh0); prefetch A(g+1, k1)
        rdA4(af, cur, 1, 0); rdB4(bq, cur, 1);
        if (more) stageA(nxt, g + 1, 1);
        asm volatile("s_waitcnt lgkmcnt(0)" ::: "memory");
        __builtin_amdgcn_sched_barrier(0);
        mfma16(af, bq, 0);
        __builtin_amdgcn_sched_barrier(0);
        __builtin_amdgcn_s_barrier();
        __builtin_amdgcn_sched_barrier(0);

        // phase 3: (k1, mh1); prefetch B(g+1, k1); confirm (g+1, k0)
        rdA4(af, cur, 1, 1);
        if (more) stageB(nxt, g + 1, 1);
        asm volatile("s_waitcnt lgkmcnt(0)" ::: "memory");
        __builtin_amdgcn_sched_barrier(0);
        mfma16(af, bq, 1);
        __builtin_amdgcn_sched_barrier(0);
        if (more) asm volatile("s_waitcnt vmcnt(4)" ::: "memory");
        __builtin_amdgcn_s_barrier();
        __builtin_amdgcn_sched_barrier(0);
    }

    if (SUMMODE) {
        // wave row-group wrM owns one batch-half: bh = mtile*2 + wrM
        const int bh = mtile * 2 + wrM;
        const int batch = bh & 511, half = bh >> 9;
#pragma unroll
        for (int j = 0; j < 4; ++j) {
            float s = 0.f;
#pragma unroll
            for (int i = 0; i < 8; ++i)
#pragma unroll
                for (int r = 0; r < 4; ++r) s += fmaxf(acc[i][j][r], 0.f);
            s += __shfl_xor(s, 16);
            s += __shfl_xor(s, 32);
            if (lk == 0)
                ((float*)C)[(size_t)batch * 1024 + half * 512 +
                            n0 + wrN * 64 + j * 16 + lr] = s;
        }
        return;
    }

    const int lk4 = lk * 4;
#pragma unroll
    for (int i = 0; i < 8; ++i) {
        const int grow = m0 + wrM * 128 + i * 16 + lk4;
#pragma unroll
        for (int j = 0; j < 4; ++j) {
            const int gcol = n0 + wrN * 64 + j * 16 + lr;
#pragma unroll
            for (int r = 0; r < 4; ++r) {
                float v = acc[i][j][r];
                if (RELU) v = fmaxf(v, 0.f);
                store_c(C + (size_t)(grow + r) * N + gcol, v);
            }
        }
    }
}

// X fp32 -> bf16 convert: xb[0..HOFFE) = premise, [HOFFE..) = hypothesis.
__global__ __launch_bounds__(256) void xcvt_kernel(
    const float* __restrict__ P, const float* __restrict__ H,
    bf16_t* __restrict__ X)
{
    const size_t NG = 8388608;
    for (size_t g = (size_t)blockIdx.x * 256 + threadIdx.x; g < NG;
         g += (size_t)gridDim.x * 256) {
        size_t i = g * 8;
        const float* s = (i < HOFFE) ? (P + i) : (H + (i - HOFFE));
        float4 f0 = ld4(s), f1 = ld4(s + 4);
        uint4 u = { pk2(f0.x, f0.y), pk2(f0.z, f0.w),
                    pk2(f1.x, f1.y), pk2(f1.z, f1.w) };
        *reinterpret_cast<uint4*>(X + i) = u;
    }
}

// ---------------------------------------------------------------------------
// 2-phase 128x128 MFMA GEMM (scores + path-B fp32-A GEMMs).
// ---------------------------------------------------------------------------
template <typename TA1, typename TC, bool RELU, int SUMMODE>
__global__ __launch_bounds__(256) void mfma_gemm_kernel(
    const TA1* __restrict__ A1, const bf16_t* __restrict__ A2, int K1,
    const bf16_t* __restrict__ Wt, TC* __restrict__ C,
    int M, int N, int K,
    long long saA, long long saB, long long saC)
{
    __shared__ bf16_t As[4096];
    __shared__ bf16_t Bs[4096];
    __shared__ float red[8][128];

    const int tid = threadIdx.x;
    const int z = blockIdx.z;

    const int nwg = gridDim.x * gridDim.y;
    const int swz = xcd_swizzle(blockIdx.y * gridDim.x + blockIdx.x, nwg);
    const int mtile = swz / gridDim.x;
    const int ntile = swz - mtile * gridDim.x;
    const int m0 = mtile * 128;
    const int n0 = ntile * 128;

    const TA1* a1    = A1 + (size_t)z * saA;
    const bf16_t* wt = Wt + (size_t)z * saB;

    const int l = tid & 63;
    const int w = tid >> 6;
    const int wr = w >> 1, wc = w & 1;
    const int lr = l & 15, lk = l >> 4;

    f32x4 acc[4][4];
#pragma unroll
    for (int m = 0; m < 4; ++m)
#pragma unroll
        for (int n = 0; n < 4; ++n) acc[m][n] = {0.f, 0.f, 0.f, 0.f};

    for (int kt = 0; kt < K; kt += 32) {
        if (kt < K1)
            stage_any(a1 + (size_t)m0 * K1 + kt, K1, As, tid);
        else
            stage_bf16(A2 + (size_t)m0 * (K - K1) + (kt - K1), K - K1, As, tid);
        stage_bf16(wt + (size_t)n0 * K + kt, K, Bs, tid);
        __syncthreads();

        bf16x8 af[4], bfr[4];
#pragma unroll
        for (int m = 0; m < 4; ++m)
            af[m] = *reinterpret_cast<const bf16x8*>(
                As + (wr * 64 + m * 16 + lr) * 32 + lk * 8);
#pragma unroll
        for (int n = 0; n < 4; ++n)
            bfr[n] = *reinterpret_cast<const bf16x8*>(
                Bs + (wc * 64 + n * 16 + lr) * 32 + lk * 8);
#pragma unroll
        for (int m = 0; m < 4; ++m)
#pragma unroll
            for (int n = 0; n < 4; ++n)
                acc[m][n] = __builtin_amdgcn_mfma_f32_16x16x32_bf16(
                    af[m], bfr[n], acc[m][n], 0, 0, 0);
        __syncthreads();
    }

    if (SUMMODE) {
        const int slot = wr * 4 + lk;
#pragma unroll
        for (int n = 0; n < 4; ++n) {
            float cs = 0.f;
#pragma unroll
            for (int m = 0; m < 4; ++m)
#pragma unroll
                for (int r = 0; r < 4; ++r)
                    cs += fmaxf(acc[m][n][r], 0.f);
            red[slot][wc * 64 + n * 16 + lr] = cs;
        }
        __syncthreads();
        if (tid < 128) {
            float s = 0.f;
#pragma unroll
            for (int s3 = 0; s3 < 8; ++s3) s += red[s3][tid];
            const int batch = mtile & 511, half = mtile >> 9;
            ((float*)C)[(size_t)batch * 1024 + half * 512 + n0 + tid] = s;
        }
        return;
    }

    TC* cp = C + (size_t)z * saC;
    const int lk4 = lk * 4;
#pragma unroll
    for (int m = 0; m < 4; ++m) {
        const int grow = m0 + wr * 64 + m * 16 + lk4;
#pragma unroll
        for (int n = 0; n < 4; ++n) {
            const int gcol = n0 + wc * 64 + n * 16 + lr;
#pragma unroll
            for (int r = 0; r < 4; ++r) {
                float v = acc[m][n][r];
                if (RELU) v = fmaxf(v, 0.f);
                store_c(cp + (size_t)(grow + r) * N + gcol, v);
            }
        }
    }
}

// ---------------------------------------------------------------------------
// Small-matrix MFMA GEMM: 64x64 tile (aggregate FFN).
// ---------------------------------------------------------------------------
template <bool RELU>
__global__ __launch_bounds__(256) void mfma_gemm_small(
    const float* __restrict__ A, const bf16_t* __restrict__ Wt,
    float* __restrict__ C, int M, int N, int K)
{
    __shared__ bf16_t As[2048];
    __shared__ bf16_t Bs[2048];

    const int tid = threadIdx.x;
    const int nwg = gridDim.x * gridDim.y;
    const int swz = xcd_swizzle(blockIdx.y * gridDim.x + blockIdx.x, nwg);
    const int mtile = swz / gridDim.x;
    const int ntile = swz - mtile * gridDim.x;
    const int m0 = mtile * 64;
    const int n0 = ntile * 64;

    const int l = tid & 63, w = tid >> 6;
    const int wr = w >> 1, wc = w & 1;
    const int lr = l & 15, lk = l >> 4;

    f32x4 acc[2][2];
#pragma unroll
    for (int m = 0; m < 2; ++m)
#pragma unroll
        for (int n = 0; n < 2; ++n) acc[m][n] = {0.f, 0.f, 0.f, 0.f};

    const int arow = tid >> 2;
    const int aseg = (tid & 3) * 8;

    for (int kt = 0; kt < K; kt += 32) {
        const float* s = A + (size_t)(m0 + arow) * K + kt + aseg;
        float4 f0 = ld4(s), f1 = ld4(s + 4);
        uint4 u = { pk2(f0.x, f0.y), pk2(f0.z, f0.w),
                    pk2(f1.x, f1.y), pk2(f1.z, f1.w) };
        __syncthreads();
        *reinterpret_cast<uint4*>(As + arow * 32 + aseg) = u;
        {
            const int row = w * 16 + (l >> 2);
            const int ce  = (l & 3) * 8;
            gload_lds16(Wt + (size_t)(n0 + row) * K + kt + ce, Bs + w * 512);
        }
        __syncthreads();

        bf16x8 af[2], bfr[2];
#pragma unroll
        for (int m = 0; m < 2; ++m)
            af[m] = *reinterpret_cast<const bf16x8*>(
                As + (wr * 32 + m * 16 + lr) * 32 + lk * 8);
#pragma unroll
        for (int n = 0; n < 2; ++n)
            bfr[n] = *reinterpret_cast<const bf16x8*>(
                Bs + (wc * 32 + n * 16 + lr) * 32 + lk * 8);
#pragma unroll
        for (int m = 0; m < 2; ++m)
#pragma unroll
            for (int n = 0; n < 2; ++n)
                acc[m][n] = __builtin_amdgcn_mfma_f32_16x16x32_bf16(
                    af[m], bfr[n], acc[m][n], 0, 0, 0);
    }

    const int lk4 = lk * 4;
#pragma unroll
    for (int m = 0; m < 2; ++m) {
        const int grow = m0 + wr * 32 + m * 16 + lk4;
#pragma unroll
        for (int n = 0; n < 2; ++n) {
            const int gcol = n0 + wc * 32 + n * 16 + lr;
#pragma unroll
            for (int r = 0; r < 4; ++r) {
                float v = acc[m][n][r];
                if (RELU) v = fmaxf(v, 0.f);
                C[(size_t)(grow + r) * N + gcol] = v;
            }
        }
    }
}

// ---------------------------------------------------------------------------
// Fused softmax + alignment via MFMA. grid (512 batches, 2 modes).
// ---------------------------------------------------------------------------
__device__ inline unsigned pkpair(const float* s, int k, int col) {
    return pk2(s[(size_t)k * 512 + col], s[(size_t)(k + 1) * 512 + col]);
}
__device__ inline unsigned pkpair(const bf16_t* s, int k, int col) {
    return ((unsigned)s[(size_t)(k + 1) * 512 + col] << 16)
         | (unsigned)s[(size_t)k * 512 + col];
}

template <typename TS>
__global__ __launch_bounds__(256) void align_mfma_kernel(
    const float* __restrict__ S, const TS* __restrict__ prem,
    const TS* __restrict__ hyp, bf16_t* __restrict__ Out)
{
    const int b = blockIdx.x;
    const int mode = blockIdx.y;
    __shared__ bf16_t E[128][136];
    __shared__ bf16_t Bs[128][36];

    const int tid = threadIdx.x;
    const float* sp  = S + (size_t)b * 16384;
    const TS* src = (mode == 0 ? hyp : prem) + (size_t)b * 65536;
    bf16_t* outp = Out + (size_t)mode * HOFFE + (size_t)b * 65536;

    if (mode == 0) {
        const int r = tid >> 1, seg = (tid & 1) * 64;
#pragma unroll
        for (int i = 0; i < 16; ++i) {
            float4 v = ld4(sp + (size_t)r * 128 + seg + i * 4);
            uint2 u = { pk2(v.x, v.y), pk2(v.z, v.w) };
            *reinterpret_cast<uint2*>(&E[r][seg + i * 4]) = u;
        }
    } else {
#pragma unroll
        for (int it = 0; it < 16; ++it) {
            int i = tid + it * 256;
            int c = i >> 5, r4 = (i & 31) << 2;
            float4 v = ld4(sp + (size_t)c * 128 + r4);
            E[r4 + 0][c] = f2bf(v.x); E[r4 + 1][c] = f2bf(v.y);
            E[r4 + 2][c] = f2bf(v.z); E[r4 + 3][c] = f2bf(v.w);
        }
    }
    __syncthreads();

    {
        const int r = tid >> 1, seg = (tid & 1) * 64;
        float m = -1e30f;
#pragma unroll
        for (int i = 0; i < 32; ++i) {
            unsigned u = *reinterpret_cast<const unsigned*>(&E[r][seg + i * 2]);
            m = fmaxf(m, fmaxf(bf2f((bf16_t)(u & 0xffff)), bf2f((bf16_t)(u >> 16))));
        }
        m = fmaxf(m, __shfl_xor(m, 1));
        float s = 0.f;
#pragma unroll
        for (int i = 0; i < 32; ++i) {
            unsigned u = *reinterpret_cast<const unsigned*>(&E[r][seg + i * 2]);
            s += __expf(bf2f((bf16_t)(u & 0xffff)) - m)
               + __expf(bf2f((bf16_t)(u >> 16)) - m);
        }
        s += __shfl_xor(s, 1);
        const float inv = 1.f / s;
#pragma unroll
        for (int i = 0; i < 32; ++i) {
            unsigned u = *reinterpret_cast<const unsigned*>(&E[r][seg + i * 2]);
            float p0 = __expf(bf2f((bf16_t)(u & 0xffff)) - m) * inv;
            float p1 = __expf(bf2f((bf16_t)(u >> 16)) - m) * inv;
            *reinterpret_cast<unsigned*>(&E[r][seg + i * 2]) = pk2(p0, p1);
        }
    }

    const int l = tid & 63, w = tid >> 6;
    const int wr = w >> 1, wc = w & 1;
    const int lr = l & 15, lk = l >> 4;
    const int sn  = tid & 127;
    const int skh = tid >> 7;

    for (int nt = 0; nt < 4; ++nt) {
        const int n0 = nt * 128;
        f32x4 acc[4][4];
#pragma unroll
        for (int m = 0; m < 4; ++m)
#pragma unroll
            for (int n = 0; n < 4; ++n) acc[m][n] = {0.f, 0.f, 0.f, 0.f};

        for (int kt = 0; kt < 4; ++kt) {
            const int k0 = kt * 32;
            unsigned pkv[8];
#pragma unroll
            for (int j = 0; j < 8; ++j) {
                const int k = k0 + (skh * 8 + j) * 2;
                pkv[j] = pkpair(src, k, n0 + sn);
            }
            __syncthreads();
#pragma unroll
            for (int j = 0; j < 8; ++j)
                *reinterpret_cast<unsigned*>(&Bs[sn][(skh * 8 + j) * 2]) = pkv[j];
            __syncthreads();

            bf16x8 af[4], bfr[4];
#pragma unroll
            for (int m = 0; m < 4; ++m)
                af[m] = *reinterpret_cast<const bf16x8*>(
                    &E[wr * 64 + m * 16 + lr][k0 + lk * 8]);
#pragma unroll
            for (int n = 0; n < 4; ++n) {
                const bf16_t* bp = &Bs[wc * 64 + n * 16 + lr][lk * 8];
                union { bf16x8 v; uint2 u[2]; } t2;
                t2.u[0] = *reinterpret_cast<const uint2*>(bp);
                t2.u[1] = *reinterpret_cast<const uint2*>(bp + 4);
                bfr[n] = t2.v;
            }
#pragma unroll
            for (int m = 0; m < 4; ++m)
#pragma unroll
                for (int n = 0; n < 4; ++n)
                    acc[m][n] = __builtin_amdgcn_mfma_f32_16x16x32_bf16(
                        af[m], bfr[n], acc[m][n], 0, 0, 0);
        }

        const int lk4 = lk * 4;
#pragma unroll
        for (int m = 0; m < 4; ++m) {
            const int grow = wr * 64 + m * 16 + lk4;
#pragma unroll
            for (int n = 0; n < 4; ++n) {
                const int gcol = n0 + wc * 64 + n * 16 + lr;
#pragma unroll
                for (int r = 0; r < 4; ++r)
                    outp[(size_t)(grow + r) * 512 + gcol] = f2bf(acc[m][n][r]);
            }
        }
        __syncthreads();
    }
}

// Weight convert+transpose: W fp32 [K,N] -> Wt bf16 [N,K]. Grid (K/32, N/32).
__global__ __launch_bounds__(256) void wcvt_transpose(
    const float* __restrict__ W, bf16_t* __restrict__ Wt, int K, int N)
{
    __shared__ float t[32][33];
    const int k0 = blockIdx.x * 32, n0 = blockIdx.y * 32;
    const int r = threadIdx.x >> 3;
    const int c = (threadIdx.x & 7) * 4;
    float4 v = ld4(W + (size_t)(k0 + r) * N + n0 + c);
    t[r][c] = v.x; t[r][c + 1] = v.y; t[r][c + 2] = v.z; t[r][c + 3] = v.w;
    __syncthreads();
    ushort4 o;
    o.x = f2bf(t[c + 0][r]); o.y = f2bf(t[c + 1][r]);
    o.z = f2bf(t[c + 2][r]); o.w = f2bf(t[c + 3][r]);
    *reinterpret_cast<ushort4*>(Wt + (size_t)(n0 + r) * K + k0 + c) = o;
}

// ===========================================================================
// Round-2 kernels (VALU path; fallback only)
// ===========================================================================

template <typename TA1, typename TA2, typename TC>
__global__ __launch_bounds__(256) void gemm_relu_kernel(
    const TA1* __restrict__ A1, const TA2* __restrict__ A2, int K1,
    const float* __restrict__ W, TC* __restrict__ C,
    int M, int N, int K)
{
    __shared__ __align__(16) float As[8][132];
    __shared__ __align__(16) float Bs[8][132];

    const int tid = threadIdx.x;
    const int tx = tid & 15;
    const int ty = tid >> 4;
    const int m0 = blockIdx.y * 128;
    const int n0 = blockIdx.x * 128;

    const int arow = tid >> 1;
    const int apart = tid & 1;
    const int brow = tid >> 5;
    const int bcol = (tid & 31) << 2;

    float acc[8][8];
#pragma unroll
    for (int i = 0; i < 8; ++i)
#pragma unroll
        for (int j = 0; j < 8; ++j) acc[i][j] = 0.f;

    for (int kt = 0; kt < K; kt += 8) {
        float4 av;
        if (kt < K1)
            av = ld4(A1 + (size_t)(m0 + arow) * K1 + kt + apart * 4);
        else
            av = ld4(A2 + (size_t)(m0 + arow) * (K - K1) + (kt - K1) + apart * 4);
        float4 bv = ld4(W + (size_t)(kt + brow) * N + n0 + bcol);

        __syncthreads();
        As[apart * 4 + 0][arow] = av.x;
        As[apart * 4 + 1][arow] = av.y;
        As[apart * 4 + 2][arow] = av.z;
        As[apart * 4 + 3][arow] = av.w;
        *reinterpret_cast<float4*>(&Bs[brow][bcol]) = bv;
        __syncthreads();

#pragma unroll
        for (int k = 0; k < 8; ++k) {
            float4 a0 = *reinterpret_cast<const float4*>(&As[k][ty * 8]);
            float4 a1 = *reinterpret_cast<const float4*>(&As[k][ty * 8 + 4]);
            float4 b0 = *reinterpret_cast<const float4*>(&Bs[k][tx * 8]);
            float4 b1 = *reinterpret_cast<const float4*>(&Bs[k][tx * 8 + 4]);
            float a[8] = {a0.x, a0.y, a0.z, a0.w, a1.x, a1.y, a1.z, a1.w};
            float b[8] = {b0.x, b0.y, b0.z, b0.w, b1.x, b1.y, b1.z, b1.w};
#pragma unroll
            for (int i = 0; i < 8; ++i)
#pragma unroll
                for (int j = 0; j < 8; ++j)
                    acc[i][j] = fmaf(a[i], b[j], acc[i][j]);
        }
    }

#pragma unroll
    for (int i = 0; i < 8; ++i) {
        float4 v0, v1;
        v0.x = fmaxf(acc[i][0], 0.f); v0.y = fmaxf(acc[i][1], 0.f);
        v0.z = fmaxf(acc[i][2], 0.f); v0.w = fmaxf(acc[i][3], 0.f);
        v1.x = fmaxf(acc[i][4], 0.f); v1.y = fmaxf(acc[i][5], 0.f);
        v1.z = fmaxf(acc[i][6], 0.f); v1.w = fmaxf(acc[i][7], 0.f);
        size_t off = (size_t)(m0 + ty * 8 + i) * N + n0 + tx * 8;
        st4(C + off, v0);
        st4(C + off + 4, v1);
    }
}

__global__ __launch_bounds__(256) void scores_valu_kernel(
    const bf16_t* __restrict__ Pp, const bf16_t* __restrict__ Ph,
    float* __restrict__ S)
{
    const int b = blockIdx.x;
    __shared__ __align__(16) float Ap[16][132];
    __shared__ __align__(16) float Bh[16][132];

    const int tid = threadIdx.x;
    const int tx = tid & 15, ty = tid >> 4;
    const bf16_t* pa = Pp + (size_t)b * 65536;
    const bf16_t* pb = Ph + (size_t)b * 65536;
    const int lrow = tid >> 2;
    const int lq = tid & 3;

    float acc[8][8];
#pragma unroll
    for (int i = 0; i < 8; ++i)
#pragma unroll
        for (int j = 0; j < 8; ++j) acc[i][j] = 0.f;

    for (int kt = 0; kt < 512; kt += 16) {
        __syncthreads();
#pragma unroll
        for (int h = 0; h < 2; ++h) {
            int row = lrow + h * 64;
            float4 v = ld4(pa + (size_t)row * 512 + kt + lq * 4);
            Ap[lq * 4 + 0][row] = v.x; Ap[lq * 4 + 1][row] = v.y;
            Ap[lq * 4 + 2][row] = v.z; Ap[lq * 4 + 3][row] = v.w;
            float4 w2 = ld4(pb + (size_t)row * 512 + kt + lq * 4);
            Bh[lq * 4 + 0][row] = w2.x; Bh[lq * 4 + 1][row] = w2.y;
            Bh[lq * 4 + 2][row] = w2.z; Bh[lq * 4 + 3][row] = w2.w;
        }
        __syncthreads();
#pragma unroll
        for (int k = 0; k < 16; ++k) {
            float4 a0 = *reinterpret_cast<const float4*>(&Ap[k][ty * 8]);
            float4 a1 = *reinterpret_cast<const float4*>(&Ap[k][ty * 8 + 4]);
            float4 b0 = *reinterpret_cast<const float4*>(&Bh[k][tx * 8]);
            float4 b1 = *reinterpret_cast<const float4*>(&Bh[k][tx * 8 + 4]);
            float a[8] = {a0.x, a0.y, a0.z, a0.w, a1.x, a1.y, a1.z, a1.w};
            float b[8] = {b0.x, b0.y, b0.z, b0.w, b1.x, b1.y, b1.z, b1.w};
#pragma unroll
            for (int i = 0; i < 8; ++i)
#pragma unroll
                for (int j = 0; j < 8; ++j)
                    acc[i][j] = fmaf(a[i], b[j], acc[i][j]);
        }
    }

    float* sp = S + (size_t)b * 16384;
#pragma unroll
    for (int i = 0; i < 8; ++i) {
        float4 v0 = {acc[i][0], acc[i][1], acc[i][2], acc[i][3]};
        float4 v1 = {acc[i][4], acc[i][5], acc[i][6], acc[i][7]};
        size_t off = (size_t)(ty * 8 + i) * 128 + tx * 8;
        *reinterpret_cast<float4*>(sp + off)     = v0;
        *reinterpret_cast<float4*>(sp + off + 4) = v1;
    }
}

template <int MODE>
__global__ __launch_bounds__(256) void align_kernel(
    const float* __restrict__ S, const float* __restrict__ Src,
    bf16_t* __restrict__ Out)
{
    const int b = blockIdx.x;
    __shared__ __align__(16) float E[64][132];
    __shared__ __align__(16) float Hs[16][132];
    __shared__ float statm[64], stati[64];

    const int tid = threadIdx.x;
    const int ty = tid >> 5;
    const int tx = tid & 31;
    const float* sp = S + (size_t)b * 16384;
    const float* src = Src + (size_t)b * 65536;
    bf16_t* outp = Out + (size_t)b * 65536;

    for (int h0 = 0; h0 < 128; h0 += 64) {
        __syncthreads();
        if (MODE == 0) {
            for (int idx = tid; idx < 2048; idx += 256) {
                int r = idx >> 5, c4 = (idx & 31) << 2;
                float4 v = ld4(sp + (size_t)(h0 + r) * 128 + c4);
                E[r][c4 + 0] = v.x; E[r][c4 + 1] = v.y;
                E[r][c4 + 2] = v.z; E[r][c4 + 3] = v.w;
            }
        } else {
            for (int idx = tid; idx < 2048; idx += 256) {
                int c = idx >> 4, r4 = (idx & 15) << 2;
                float4 v = ld4(sp + (size_t)c * 128 + h0 + r4);
                E[r4 + 0][c] = v.x; E[r4 + 1][c] = v.y;
                E[r4 + 2][c] = v.z; E[r4 + 3][c] = v.w;
            }
        }
        __syncthreads();

        if (tid < 64) {
            float m = -1e30f;
            for (int c = 0; c < 128; ++c) m = fmaxf(m, E[tid][c]);
            float s = 0.f;
            for (int c = 0; c < 128; ++c) s += __expf(E[tid][c] - m);
            statm[tid] = m;
            stati[tid] = 1.f / s;
        }
        __syncthreads();

        for (int idx = tid; idx < 8192; idx += 256) {
            int r = idx >> 7, c = idx & 127;
            E[r][c] = __expf(E[r][c] - statm[r]) * stati[r];
        }

        for (int dc = 0; dc < 4; ++dc) {
            float acc[8][4];
#pragma unroll
            for (int i = 0; i < 8; ++i)
#pragma unroll
                for (int j = 0; j < 4; ++j) acc[i][j] = 0.f;

            for (int ct = 0; ct < 8; ++ct) {
                __syncthreads();
                for (int idx = tid; idx < 512; idx += 256) {
                    int r = idx >> 5, c4 = (idx & 31) << 2;
                    float4 v = ld4(src + (size_t)(ct * 16 + r) * 512 + dc * 128 + c4);
                    *reinterpret_cast<float4*>(&Hs[r][c4]) = v;
                }
                __syncthreads();
#pragma unroll
                for (int k = 0; k < 16; ++k) {
                    int c = ct * 16 + k;
                    float a[8];
#pragma unroll
                    for (int i = 0; i < 8; ++i) a[i] = E[ty * 8 + i][c];
                    float4 b4 = *reinterpret_cast<const float4*>(&Hs[k][tx * 4]);
                    float bb[4] = {b4.x, b4.y, b4.z, b4.w};
#pragma unroll
                    for (int i = 0; i < 8; ++i)
#pragma unroll
                        for (int j = 0; j < 4; ++j)
                            acc[i][j] = fmaf(a[i], bb[j], acc[i][j]);
                }
            }
#pragma unroll
            for (int i = 0; i < 8; ++i) {
                float4 v = {acc[i][0], acc[i][1], acc[i][2], acc[i][3]};
                st4(outp + (size_t)(h0 + ty * 8 + i) * 512 + dc * 128 + tx * 4, v);
            }
        }
    }
}

__global__ __launch_bounds__(128) void seqsum_kernel(
    const bf16_t* __restrict__ Cmp, float* __restrict__ Agg)
{
    const int b = blockIdx.x;
    const int half = blockIdx.y;
    const bf16_t* base = Cmp + (size_t)half * HOFFE + (size_t)b * 65536 + threadIdx.x * 4;
    float4 s = {0.f, 0.f, 0.f, 0.f};
    for (int r = 0; r < 128; ++r) {
        ushort4 u = *reinterpret_cast<const ushort4*>(base + (size_t)r * 512);
        s.x += bf2f(u.x); s.y += bf2f(u.y); s.z += bf2f(u.z); s.w += bf2f(u.w);
    }
    *reinterpret_cast<float4*>(Agg + (size_t)b * 1024 + half * 512 + threadIdx.x * 4) = s;
}

__global__ __launch_bounds__(64) void scorer_kernel(
    const float* __restrict__ H, const float* __restrict__ Wsc,
    float* __restrict__ Out)
{
    const int row = blockIdx.x;
    const int l = threadIdx.x;
    float a0 = 0.f, a1 = 0.f;
    for (int h = l; h < 512; h += 64) {
        float v = H[(size_t)row * 512 + h];
        a0 = fmaf(v, Wsc[h * 2 + 0], a0);
        a1 = fmaf(v, Wsc[h * 2 + 1], a1);
    }
#pragma unroll
    for (int off = 32; off > 0; off >>= 1) {
        a0 += __shfl_down(a0, off);
        a1 += __shfl_down(a1, off);
    }
    if (l == 0) {
        float m = fmaxf(a0, a1);
        float e0 = __expf(a0 - m), e1 = __expf(a1 - m);
        float inv = 1.f / (e0 + e1);
        Out[row * 2 + 0] = e0 * inv;
        Out[row * 2 + 1] = e1 * inv;
    }
}

// ===========================================================================
extern "C" void kernel_launch(void* const* d_in, const int* in_sizes, int n_in,
                              void* d_out, int out_size, void* d_ws, size_t ws_size,
                              hipStream_t stream)
{
    const float* premise    = (const float*)d_in[0];
    const float* hypothesis = (const float*)d_in[1];
    const float* aw0 = (const float*)d_in[2];
    const float* aw1 = (const float*)d_in[3];
    const float* cw0 = (const float*)d_in[4];
    const float* cw1 = (const float*)d_in[5];
    const float* gw0 = (const float*)d_in[6];
    const float* gw1 = (const float*)d_in[7];
    const float* wsc = (const float*)d_in[8];
    float* out = (float*)d_out;

    char* ws = (char*)d_ws;
    dim3 blk(256);
    dim3 blk8(512);

    const size_t MB128 = 134217728ull;
    const size_t NEED_A = 3 * MB128 + 4194304 + 4194304;
    const size_t NEED_B = 2 * MB128 + 4194304 + 4194304;

    if (ws_size >= NEED_A) {
        // ---------------- path A: full pipeline, all-bf16 big GEMMs --------
        bf16_t* xb = (bf16_t*)ws;                       // [131072,512] bf16
        bf16_t* r0 = (bf16_t*)(ws + MB128);             // T1 -> (scores) -> C1
        bf16_t* r1 = (bf16_t*)(ws + 2 * MB128);         // proj -> align
        float* scoresF = (float*)(ws + MB128);          // overlays r0 (T1 dead)
        const size_t WOFF = 3 * MB128;
        bf16_t* awt0 = (bf16_t*)(ws + WOFF);
        bf16_t* awt1 = awt0 + 262144;
        bf16_t* cwt0 = awt1 + 262144;
        bf16_t* cwt1 = cwt0 + 524288;
        bf16_t* gwt0 = cwt1 + 262144;
        bf16_t* gwt1 = gwt0 + 524288;
        float* aggF  = (float*)(ws + WOFF + 4194304);
        float* hid1F = aggF + 524288;
        float* hid2F = hid1F + 262144;

        xcvt_kernel<<<2048, blk, 0, stream>>>(premise, hypothesis, xb);
        wcvt_transpose<<<dim3(16, 16), blk, 0, stream>>>(aw0, awt0, 512, 512);
        wcvt_transpose<<<dim3(16, 16), blk, 0, stream>>>(aw1, awt1, 512, 512);
        wcvt_transpose<<<dim3(32, 16), blk, 0, stream>>>(cw0, cwt0, 1024, 512);
        wcvt_transpose<<<dim3(16, 16), blk, 0, stream>>>(cw1, cwt1, 512, 512);
        wcvt_transpose<<<dim3(32, 16), blk, 0, stream>>>(gw0, gwt0, 1024, 512);
        wcvt_transpose<<<dim3(16, 16), blk, 0, stream>>>(gw1, gwt1, 512, 512);

        // 1. Attend L1 (both sentences): T1 = relu(xb @ aw0) -> r0
        mfma_gemm_8ph<bf16_t, true, 0><<<dim3(2, 512), blk8, 0, stream>>>(
            xb, xb, 512, awt0, r0, 131072, 512, 512);
        // 2. Attend L2: proj = relu(T1 @ aw1) -> r1
        mfma_gemm_8ph<bf16_t, true, 0><<<dim3(2, 512), blk8, 0, stream>>>(
            r0, r0, 512, awt1, r1, 131072, 512, 512);
        // 3. scores[b] = proj_p[b] @ proj_h[b]^T -> scoresF (overlays r0)
        mfma_gemm_kernel<bf16_t, float, false, 0><<<dim3(1, 1, 512), blk, 0, stream>>>(
            r1, nullptr, 512, r1 + HOFFE, scoresF, 128, 128, 512,
            65536LL, 65536LL, 16384LL);
        // 4. alignments -> r1 (overwrites proj); src = bf16 xb
        align_mfma_kernel<bf16_t><<<dim3(512, 2), blk, 0, stream>>>(
            scoresF, xb, xb + HOFFE, r1);
        // 5. Compare L1: relu([xb | align] @ cw0) -> r0
        mfma_gemm_8ph<bf16_t, true, 0><<<dim3(2, 512), blk8, 0, stream>>>(
            xb, r1, 512, cwt0, r0, 131072, 512, 1024);
        // 6. Compare L2 fused seq-sum -> aggregated
        mfma_gemm_8ph<float, true, 1><<<dim3(2, 512), blk8, 0, stream>>>(
            r0, r0, 512, cwt1, aggF, 131072, 512, 512);
        // 7. Aggregate FFN + scorer
        mfma_gemm_small<true><<<dim3(8, 8), blk, 0, stream>>>(
            aggF, gwt0, hid1F, 512, 512, 1024);
        mfma_gemm_small<true><<<dim3(8, 8), blk, 0, stream>>>(
            hid1F, gwt1, hid2F, 512, 512, 512);
        scorer_kernel<<<512, 64, 0, stream>>>(hid2F, wsc, out);
    } else if (ws_size >= NEED_B) {
        // ---------------- path B: round-6 layout; 8ph for bf16-A GEMMs -----
        bf16_t* r0 = (bf16_t*)ws;
        bf16_t* r1 = (bf16_t*)(ws + MB128);
        float* scoresF = (float*)ws;
        const size_t WOFF = 2 * MB128;
        bf16_t* awt0 = (bf16_t*)(ws + WOFF);
        bf16_t* awt1 = awt0 + 262144;
        bf16_t* cwt0 = awt1 + 262144;
        bf16_t* cwt1 = cwt0 + 524288;
        bf16_t* gwt0 = cwt1 + 262144;
        bf16_t* gwt1 = gwt0 + 524288;
        float* aggF  = (float*)(ws + WOFF + 4194304);
        float* hid1F = aggF + 524288;
        float* hid2F = hid1F + 262144;

        wcvt_transpose<<<dim3(16, 16), blk, 0, stream>>>(aw0, awt0, 512, 512);
        wcvt_transpose<<<dim3(16, 16), blk, 0, stream>>>(aw1, awt1, 512, 512);
        wcvt_transpose<<<dim3(32, 16), blk, 0, stream>>>(cw0, cwt0, 1024, 512);
        wcvt_transpose<<<dim3(16, 16), blk, 0, stream>>>(cw1, cwt1, 512, 512);
        wcvt_transpose<<<dim3(32, 16), blk, 0, stream>>>(gw0, gwt0, 1024, 512);
        wcvt_transpose<<<dim3(16, 16), blk, 0, stream>>>(gw1, gwt1, 512, 512);

        mfma_gemm_kernel<float, bf16_t, true, 0><<<dim3(4, 512, 1), blk, 0, stream>>>(
            premise, nullptr, 512, awt0, r0, 65536, 512, 512, 0, 0, 0);
        mfma_gemm_kernel<float, bf16_t, true, 0><<<dim3(4, 512, 1), blk, 0, stream>>>(
            hypothesis, nullptr, 512, awt0, r0 + HOFFE, 65536, 512, 512, 0, 0, 0);
        mfma_gemm_8ph<bf16_t, true, 0><<<dim3(2, 512), blk8, 0, stream>>>(
            r0, r0, 512, awt1, r1, 131072, 512, 512);
        mfma_gemm_kernel<bf16_t, float, false, 0><<<dim3(1, 1, 512), blk, 0, stream>>>(
            r1, nullptr, 512, r1 + HOFFE, scoresF, 128, 128, 512,
            65536LL, 65536LL, 16384LL);
        align_mfma_kernel<float><<<dim3(512, 2), blk, 0, stream>>>(
            scoresF, premise, hypothesis, r1);
        mfma_gemm_kernel<float, bf16_t, true, 0><<<dim3(4, 512, 1), blk, 0, stream>>>(
            premise, r1, 512, cwt0, r0, 65536, 512, 1024, 0, 0, 0);
        mfma_gemm_kernel<float, bf16_t, true, 0><<<dim3(4, 512, 1), blk, 0, stream>>>(
            hypothesis, r1 + HOFFE, 512, cwt0, r0 + HOFFE, 65536, 512, 1024, 0, 0, 0);
        mfma_gemm_8ph<float, true, 1><<<dim3(2, 512), blk8, 0, stream>>>(
            r0, r0, 512, cwt1, aggF, 131072, 512, 512);
        mfma_gemm_small<true><<<dim3(8, 8), blk, 0, stream>>>(
            aggF, gwt0, hid1F, 512, 512, 1024);
        mfma_gemm_small<true><<<dim3(8, 8), blk, 0, stream>>>(
            hid1F, gwt1, hid2F, 512, 512, 512);
        scorer_kernel<<<512, 64, 0, stream>>>(hid2F, wsc, out);
    } else {
        // ---------------- path C: round-2 VALU fallback (complete) ---------
        bf16_t* r0 = (bf16_t*)ws;
        bf16_t* r1 = (bf16_t*)(ws + MB128);
        float* scoresF = (float*)ws;
        float* aggF  = (float*)ws;
        float* hid1F = (float*)(ws + (size_t)4194304);
        float* hid2F = (float*)(ws + (size_t)8388608);
        gemm_relu_kernel<float, bf16_t, bf16_t><<<dim3(4, 512), blk, 0, stream>>>(
            premise, nullptr, 512, aw0, r0, 65536, 512, 512);
        gemm_relu_kernel<float, bf16_t, bf16_t><<<dim3(4, 512), blk, 0, stream>>>(
            hypothesis, nullptr, 512, aw0, r0 + HOFFE, 65536, 512, 512);
        gemm_relu_kernel<bf16_t, bf16_t, bf16_t><<<dim3(4, 1024), blk, 0, stream>>>(
            r0, nullptr, 512, aw1, r1, 131072, 512, 512);
        scores_valu_kernel<<<512, blk, 0, stream>>>(r1, r1 + HOFFE, scoresF);
        align_kernel<0><<<512, blk, 0, stream>>>(scoresF, hypothesis, r1);
        align_kernel<1><<<512, blk, 0, stream>>>(scoresF, premise, r1 + HOFFE);
        gemm_relu_kernel<float, bf16_t, bf16_t><<<dim3(4, 512), blk, 0, stream>>>(
            premise, r1, 512, cw0, r0, 65536, 512, 1024);
        gemm_relu_kernel<float, bf16_t, bf16_t><<<dim3(4, 512), blk, 0, stream>>>(
            hypothesis, r1 + HOFFE, 512, cw0, r0 + HOFFE, 65536, 512, 1024);
        gemm_relu_kernel<bf16_t, bf16_t, bf16_t><<<dim3(4, 1024), blk, 0, stream>>>(
            r0, nullptr, 512, cw1, r1, 131072, 512, 512);
        seqsum_kernel<<<dim3(512, 2), 128, 0, stream>>>(r1, aggF);
        gemm_relu_kernel<float, bf16_t, float><<<dim3(4, 4), blk, 0, stream>>>(
            aggF, nullptr, 1024, gw0, hid1F, 512, 512, 1024);
        gemm_relu_kernel<float, bf16_t, float><<<dim3(4, 4), blk, 0, stream>>>(
            hid1F, nullptr, 512, gw1, hid2F, 512, 512, 512);
        scorer_kernel<<<512, 64, 0, stream>>>(hid2F, wsc, out);
    }
}